// Round 6
// baseline (686.970 us; speedup 1.0000x reference)
//
#include <hip/hip_runtime.h>

#define N_NODES 100000
#define N_EDGES 1600000
#define N_GRAPHS 1000
#define D 128
#define LATENT 64
#define EPS 1e-5f
#define NB ((N_NODES + 255) / 256)   // 391
#define NBUCK 196                    // buckets of 512 nodes: bucket = dst >> 9
#define BSH 9
#define CONVX_BLOCKS ((N_NODES * D / 4 + 255) / 256)   // 12500

typedef unsigned short u16;
typedef unsigned int u32;
typedef __attribute__((ext_vector_type(8))) short short8;   // 8 bf16 = 4 VGPR (MFMA A/B frag)
typedef __attribute__((ext_vector_type(4))) float f32x4;    // MFMA C/D frag

__device__ __forceinline__ float bf2f(u32 u) {
    union { u32 i; float f; } c; c.i = u << 16; return c.f;
}
__device__ __forceinline__ u16 f2bf(float f) {
    union { float f; u32 u; } c; c.f = f;
    u32 u = c.u;
    return (u16)((u + 0x7fffu + ((u >> 16) & 1u)) >> 16);   // RNE
}

// ---------------- fused init: weight convert + x convert + zero small bufs ----------------

__global__ void init_misc(const float* __restrict__ W1, const float* __restrict__ W2,
                          u16* __restrict__ Wt, const float* __restrict__ x,
                          u16* __restrict__ xb, float* __restrict__ colsumAll,
                          int* __restrict__ counters, int* __restrict__ bhist,
                          int* __restrict__ gs, int* __restrict__ ge) {
    int b = blockIdx.x, t = threadIdx.x;
    if (b < 6) {
        const float* src = (b < 3) ? (W1 + (size_t)b * D * D) : (W2 + (size_t)(b - 3) * D * D);
        u16* dst = Wt + (size_t)b * D * D;
        for (int i = t; i < D * D; i += 256) {
            int k = i >> 7, n = i & 127;
            dst[n * D + k] = f2bf(src[i]);
        }
    } else if (b == 6) {
        for (int i = t; i < 6 * 256; i += 256) colsumAll[i] = 0.f;
        if (t < 3) counters[t] = 0;
        if (t < NBUCK) bhist[t] = 0;
        for (int i = t; i < N_GRAPHS; i += 256) { gs[i] = 0x7fffffff; ge[i] = 0; }
    } else {
        int idx = (b - 7) * 256 + t;
        if (idx < N_NODES * D / 4) {
            float4 v = *(const float4*)&x[(size_t)idx * 4];
            u32 lo = (u32)f2bf(v.x) | ((u32)f2bf(v.y) << 16);
            u32 hi = (u32)f2bf(v.z) | ((u32)f2bf(v.w) << 16);
            *(uint2*)&xb[(size_t)idx * 4] = make_uint2(lo, hi);
        }
    }
}

// ---------------- bucketed CSR build ----------------

__global__ void bucket_hist(const int* __restrict__ dst, int* __restrict__ bhist) {
    __shared__ int cnt[256];
    int t = threadIdx.x;
    cnt[t] = 0;
    __syncthreads();
    int base = blockIdx.x * 4096 + t * 16;
#pragma unroll
    for (int i = 0; i < 16; ++i) {
        int e = base + i;
        if (e < N_EDGES) atomicAdd(&cnt[dst[e] >> BSH], 1);
    }
    __syncthreads();
    if (t < NBUCK && cnt[t] > 0) atomicAdd(&bhist[t], cnt[t]);
}

__global__ void bucket_scan(const int* __restrict__ bhist, int* __restrict__ bstart,
                            int* __restrict__ gbcur) {
    __shared__ int s[256];
    int t = threadIdx.x;
    int v = (t < NBUCK) ? bhist[t] : 0;
    s[t] = v;
    __syncthreads();
    for (int off = 1; off < 256; off <<= 1) {
        int a = (t >= off) ? s[t - off] : 0;
        __syncthreads();
        s[t] += a;
        __syncthreads();
    }
    if (t < NBUCK) { int ex = s[t] - v; bstart[t] = ex; gbcur[t] = ex; }
    if (t == NBUCK - 1) bstart[NBUCK] = s[t];
}

__global__ __launch_bounds__(256)
void bucket_scatter(const int* __restrict__ src, const int* __restrict__ dst,
                    int* __restrict__ gbcur, int* __restrict__ ebs, int* __restrict__ ebd) {
    __shared__ int cnt[256], loff[256], basev[256], scn[256];
    __shared__ int psrc[4096], pdst[4096];
    __shared__ unsigned char pbkt[4096];
    int t = threadIdx.x;
    cnt[t] = 0;
    __syncthreads();
    int ebase = blockIdx.x * 4096;
    int d[16], sv[16], b[16], r[16];
#pragma unroll
    for (int i = 0; i < 16; ++i) {
        int e = ebase + t * 16 + i;
        bool ok = e < N_EDGES;
        d[i] = ok ? dst[e] : 0;
        sv[i] = ok ? src[e] : 0;
        b[i] = ok ? (d[i] >> BSH) : -1;
    }
#pragma unroll
    for (int i = 0; i < 16; ++i)
        r[i] = (b[i] >= 0) ? atomicAdd(&cnt[b[i]], 1) : 0;
    __syncthreads();
    int c = cnt[t];
    scn[t] = c;
    __syncthreads();
    for (int off = 1; off < 256; off <<= 1) {
        int a = (t >= off) ? scn[t - off] : 0;
        __syncthreads();
        scn[t] += a;
        __syncthreads();
    }
    loff[t] = scn[t] - c;
    if (c > 0) basev[t] = atomicAdd(&gbcur[t], c);
    __syncthreads();
#pragma unroll
    for (int i = 0; i < 16; ++i) {
        if (b[i] >= 0) {
            int p = loff[b[i]] + r[i];
            psrc[p] = sv[i];
            pdst[p] = d[i];
            pbkt[p] = (unsigned char)b[i];
        }
    }
    __syncthreads();
    int total = min(4096, N_EDGES - ebase);
    for (int i = t; i < total; i += 256) {
        int bb = pbkt[i];
        int g = basev[bb] + (i - loff[bb]);
        ebs[g] = psrc[i];
        ebd[g] = pdst[i];
    }
}

__global__ void hist_local(const int* __restrict__ ebd, const int* __restrict__ bstart,
                           int* __restrict__ deg) {
    __shared__ int h[512];
    int b = blockIdx.x, t = threadIdx.x;
    int nbase = b << BSH;
    h[t] = 0; h[t + 256] = 0;
    __syncthreads();
    int e0 = bstart[b], e1 = bstart[b + 1];
    for (int e = e0 + t; e < e1; e += 256)
        atomicAdd(&h[ebd[e] - nbase], 1);
    __syncthreads();
    int nlen = min(512, N_NODES - nbase);
    if (t < nlen) deg[nbase + t] = h[t];
    if (t + 256 < nlen) deg[nbase + t + 256] = h[t + 256];
}

__global__ void scan_block_sum(const int* __restrict__ deg, int* __restrict__ bsum) {
    __shared__ int s[256];
    int t = threadIdx.x;
    int i = blockIdx.x * 256 + t;
    s[t] = (i < N_NODES) ? deg[i] : 0;
    __syncthreads();
    for (int off = 128; off > 0; off >>= 1) {
        if (t < off) s[t] += s[t + off];
        __syncthreads();
    }
    if (t == 0) bsum[blockIdx.x] = s[0];
}

__global__ void scan_top(const int* __restrict__ bsum, int* __restrict__ boff) {
    __shared__ int s[512];
    int t = threadIdx.x;
    int v = (t < NB) ? bsum[t] : 0;
    s[t] = v;
    __syncthreads();
    for (int off = 1; off < 512; off <<= 1) {
        int add = (t >= off) ? s[t - off] : 0;
        __syncthreads();
        s[t] += add;
        __syncthreads();
    }
    if (t < NB) boff[t] = s[t] - v;
}

__global__ void scan_apply(const int* __restrict__ deg, const int* __restrict__ boff,
                           int* __restrict__ offsets) {
    __shared__ int s[256];
    int t = threadIdx.x;
    int i = blockIdx.x * 256 + t;
    int v = (i < N_NODES) ? deg[i] : 0;
    s[t] = v;
    __syncthreads();
    for (int off = 1; off < 256; off <<= 1) {
        int add = (t >= off) ? s[t - off] : 0;
        __syncthreads();
        s[t] += add;
        __syncthreads();
    }
    int base = boff[blockIdx.x];
    if (i < N_NODES) offsets[i] = base + s[t] - v;
    if (i == N_NODES - 1) offsets[N_NODES] = base + s[t];
}

__global__ void csr_fill_local(const int* __restrict__ ebs, const int* __restrict__ ebd,
                               const int* __restrict__ bstart, const int* __restrict__ offsets,
                               int* __restrict__ csr) {
    __shared__ int cur[512];
    int b = blockIdx.x, t = threadIdx.x;
    int nbase = b << BSH;
    int nlen = min(512, N_NODES - nbase);
    if (t < nlen) cur[t] = offsets[nbase + t];
    if (t + 256 < nlen) cur[t + 256] = offsets[nbase + t + 256];
    __syncthreads();
    int e0 = bstart[b], e1 = bstart[b + 1];
    for (int e = e0 + t; e < e1; e += 256) {
        int p = atomicAdd(&cur[ebd[e] - nbase], 1);
        csr[p] = ebs[e];
    }
}

// ---------------- aggregation: ab = bf16( x + sum_{j->i} x_j ), x in bf16 ----------------
// 16 lanes/node, uint4 (8 bf16) per lane, 8-deep load batch -> 128B in flight/thread.

__device__ __forceinline__ void acc8(float* a, uint4 v) {
    a[0] += bf2f(v.x & 0xffff); a[1] += bf2f(v.x >> 16);
    a[2] += bf2f(v.y & 0xffff); a[3] += bf2f(v.y >> 16);
    a[4] += bf2f(v.z & 0xffff); a[5] += bf2f(v.z >> 16);
    a[6] += bf2f(v.w & 0xffff); a[7] += bf2f(v.w >> 16);
}

__global__ void agg_kernel(const u16* __restrict__ xb, const int* __restrict__ csr,
                           const int* __restrict__ offsets, u16* __restrict__ ab) {
    int t = blockIdx.x * blockDim.x + threadIdx.x;
    int node = t >> 4;
    if (node >= N_NODES) return;
    int lane = t & 15;
    const uint4* xp = (const uint4*)(xb + lane * 8);   // advance: 16 uint4 per row
    float a[8] = {0, 0, 0, 0, 0, 0, 0, 0};
    acc8(a, xp[(size_t)node * 16]);
    int s = offsets[node], e = offsets[node + 1];
    int p = s;
    for (; p + 8 <= e; p += 8) {
        int j0 = csr[p], j1 = csr[p + 1], j2 = csr[p + 2], j3 = csr[p + 3];
        int j4 = csr[p + 4], j5 = csr[p + 5], j6 = csr[p + 6], j7 = csr[p + 7];
        uint4 v0 = xp[(size_t)j0 * 16];
        uint4 v1 = xp[(size_t)j1 * 16];
        uint4 v2 = xp[(size_t)j2 * 16];
        uint4 v3 = xp[(size_t)j3 * 16];
        uint4 v4 = xp[(size_t)j4 * 16];
        uint4 v5 = xp[(size_t)j5 * 16];
        uint4 v6 = xp[(size_t)j6 * 16];
        uint4 v7 = xp[(size_t)j7 * 16];
        acc8(a, v0); acc8(a, v1); acc8(a, v2); acc8(a, v3);
        acc8(a, v4); acc8(a, v5); acc8(a, v6); acc8(a, v7);
    }
    for (; p + 4 <= e; p += 4) {
        int j0 = csr[p], j1 = csr[p + 1], j2 = csr[p + 2], j3 = csr[p + 3];
        uint4 v0 = xp[(size_t)j0 * 16];
        uint4 v1 = xp[(size_t)j1 * 16];
        uint4 v2 = xp[(size_t)j2 * 16];
        uint4 v3 = xp[(size_t)j3 * 16];
        acc8(a, v0); acc8(a, v1); acc8(a, v2); acc8(a, v3);
    }
    for (; p < e; ++p)
        acc8(a, xp[(size_t)csr[p] * 16]);
    uint4 o;
    o.x = (u32)f2bf(a[0]) | ((u32)f2bf(a[1]) << 16);
    o.y = (u32)f2bf(a[2]) | ((u32)f2bf(a[3]) << 16);
    o.z = (u32)f2bf(a[4]) | ((u32)f2bf(a[5]) << 16);
    o.w = (u32)f2bf(a[6]) | ((u32)f2bf(a[7]) << 16);
    *(uint4*)&ab[(size_t)node * D + lane * 8] = o;
}

// ---------------- MFMA GEMM common geometry ----------------
// 256 thr = 4 waves, BM=128, N=128, K=128. Wave (wid): rows (wid>>1)*64, cols (wid&1)*64.
// LDS [row][k] bf16, 256B rows, XOR-swizzle byte ^= ((row&15)<<4).

// GEMM1: H = leaky(A@W1 + b1) bf16 IN PLACE over A; fused BN stats + last-block finalize.
__global__ __launch_bounds__(256, 2)
void gemm1_mfma(u16* __restrict__ AB, const u16* __restrict__ Wt,
                const float* __restrict__ bias,
                float* __restrict__ colsum, float* __restrict__ colsq,
                const float* __restrict__ gamma, const float* __restrict__ beta,
                float* __restrict__ scalev, float* __restrict__ shiftv,
                int* __restrict__ counter) {
    __shared__ u16 As[128 * 128];
    __shared__ u16 Ws[128 * 128];
    __shared__ float csumL[D], csqL[D];
    int tid = threadIdx.x;
    int row0 = blockIdx.x * 128;

    if (tid < D) { csumL[tid] = 0.f; csqL[tid] = 0.f; }
    const uint4* Wg = (const uint4*)Wt;
#pragma unroll
    for (int i = 0; i < 8; ++i) {
        int q = i * 256 + tid;
        int m = q >> 4, kc = q & 15;
        uint4 wv = Wg[q];
        *(uint4*)((char*)Ws + m * 256 + ((kc * 16) ^ ((m & 15) << 4))) = wv;
        uint4 av = make_uint4(0, 0, 0, 0);
        int gm = row0 + m;
        if (gm < N_NODES) av = *(const uint4*)&AB[(size_t)gm * D + kc * 8];
        *(uint4*)((char*)As + m * 256 + ((kc * 16) ^ ((m & 15) << 4))) = av;
    }
    __syncthreads();

    int lane = tid & 63;
    int wid = tid >> 6;
    int mbase = (wid >> 1) * 64, nbase = (wid & 1) * 64;
    int lr = lane & 15, kg = lane >> 4;
    f32x4 acc[4][4];
#pragma unroll
    for (int mt = 0; mt < 4; ++mt)
#pragma unroll
        for (int nt = 0; nt < 4; ++nt) acc[mt][nt] = (f32x4)0.0f;

    const char* Ap = (const char*)As;
    const char* Wp = (const char*)Ws;
#pragma unroll
    for (int ks = 0; ks < 4; ++ks) {
        int kb2 = ks * 64 + kg * 16;
        short8 af[4], bfr[4];
#pragma unroll
        for (int t = 0; t < 4; ++t) {
            int m = mbase + t * 16 + lr;
            af[t] = *(const short8*)(Ap + m * 256 + (kb2 ^ ((m & 15) << 4)));
            int n = nbase + t * 16 + lr;
            bfr[t] = *(const short8*)(Wp + n * 256 + (kb2 ^ ((n & 15) << 4)));
        }
#pragma unroll
        for (int mt = 0; mt < 4; ++mt)
#pragma unroll
            for (int nt = 0; nt < 4; ++nt)
                acc[mt][nt] = __builtin_amdgcn_mfma_f32_16x16x32_bf16(af[mt], bfr[nt], acc[mt][nt], 0, 0, 0);
    }

    float bv[4], ls[4] = {0, 0, 0, 0}, lq[4] = {0, 0, 0, 0};
#pragma unroll
    for (int nt = 0; nt < 4; ++nt) bv[nt] = bias[nbase + nt * 16 + lr];
#pragma unroll
    for (int mt = 0; mt < 4; ++mt) {
#pragma unroll
        for (int r = 0; r < 4; ++r) {
            int gm = row0 + mbase + mt * 16 + kg * 4 + r;
            if (gm < N_NODES) {
#pragma unroll
                for (int nt = 0; nt < 4; ++nt) {
                    float z = acc[mt][nt][r] + bv[nt];
                    z = (z >= 0.f) ? z : 0.2f * z;
                    AB[(size_t)gm * D + nbase + nt * 16 + lr] = f2bf(z);
                    ls[nt] += z; lq[nt] += z * z;
                }
            }
        }
    }
#pragma unroll
    for (int nt = 0; nt < 4; ++nt) {
        ls[nt] += __shfl_down(ls[nt], 32); ls[nt] += __shfl_down(ls[nt], 16);
        lq[nt] += __shfl_down(lq[nt], 32); lq[nt] += __shfl_down(lq[nt], 16);
    }
    if (lane < 16) {
#pragma unroll
        for (int nt = 0; nt < 4; ++nt) {
            atomicAdd(&csumL[nbase + nt * 16 + lane], ls[nt]);
            atomicAdd(&csqL[nbase + nt * 16 + lane], lq[nt]);
        }
    }
    __syncthreads();
    if (tid < D) {
        atomicAdd(&colsum[tid], csumL[tid]);
        atomicAdd(&colsq[tid], csqL[tid]);
    }
    // last-block BN finalize (replaces bn_fin kernel)
    __threadfence();
    __syncthreads();
    __shared__ int lastFlag;
    if (tid == 0) lastFlag = (atomicAdd(counter, 1) == (int)gridDim.x - 1) ? 1 : 0;
    __syncthreads();
    if (lastFlag && tid < D) {
        float s = atomicAdd(&colsum[tid], 0.0f);   // coherent device-scope read
        float q = atomicAdd(&colsq[tid], 0.0f);
        float m = s * (1.0f / N_NODES);
        float var = fmaxf(q * (1.0f / N_NODES) - m * m, 0.f);
        float sc = gamma[tid] * rsqrtf(var + EPS);
        scalev[tid] = sc;
        shiftv[tid] = beta[tid] - m * sc;
    }
}

// GEMM2: x = bf16( leaky(BN(H)@W2 + b2) + xres ), all-bf16 residual stream.
__global__ __launch_bounds__(256, 2)
void gemm2_mfma(const u16* __restrict__ HB, const u16* __restrict__ Wt,
                const float* __restrict__ bias, const float* __restrict__ scalev,
                const float* __restrict__ shiftv, const u16* __restrict__ xres,
                u16* __restrict__ xbout) {
    __shared__ u16 As[128 * 128];
    __shared__ u16 Ws[128 * 128];
    int tid = threadIdx.x;
    int row0 = blockIdx.x * 128;

    const uint4* Wg = (const uint4*)Wt;
#pragma unroll
    for (int i = 0; i < 8; ++i) {
        int q = i * 256 + tid;
        int m = q >> 4, kc = q & 15;
        uint4 wv = Wg[q];
        *(uint4*)((char*)Ws + m * 256 + ((kc * 16) ^ ((m & 15) << 4))) = wv;
        uint4 av = make_uint4(0, 0, 0, 0);
        int gm = row0 + m;
        if (gm < N_NODES) {
            uint4 h = *(const uint4*)&HB[(size_t)gm * D + kc * 8];
            float4 s0 = *(const float4*)&scalev[kc * 8];
            float4 s1 = *(const float4*)&scalev[kc * 8 + 4];
            float4 t0 = *(const float4*)&shiftv[kc * 8];
            float4 t1 = *(const float4*)&shiftv[kc * 8 + 4];
            float f0 = bf2f(h.x & 0xffff) * s0.x + t0.x;
            float f1 = bf2f(h.x >> 16)    * s0.y + t0.y;
            float f2 = bf2f(h.y & 0xffff) * s0.z + t0.z;
            float f3 = bf2f(h.y >> 16)    * s0.w + t0.w;
            float f4 = bf2f(h.z & 0xffff) * s1.x + t1.x;
            float f5 = bf2f(h.z >> 16)    * s1.y + t1.y;
            float f6 = bf2f(h.w & 0xffff) * s1.z + t1.z;
            float f7 = bf2f(h.w >> 16)    * s1.w + t1.w;
            av.x = (u32)f2bf(f0) | ((u32)f2bf(f1) << 16);
            av.y = (u32)f2bf(f2) | ((u32)f2bf(f3) << 16);
            av.z = (u32)f2bf(f4) | ((u32)f2bf(f5) << 16);
            av.w = (u32)f2bf(f6) | ((u32)f2bf(f7) << 16);
        }
        *(uint4*)((char*)As + m * 256 + ((kc * 16) ^ ((m & 15) << 4))) = av;
    }
    __syncthreads();

    int lane = tid & 63;
    int wid = tid >> 6;
    int mbase = (wid >> 1) * 64, nbase = (wid & 1) * 64;
    int lr = lane & 15, kg = lane >> 4;
    f32x4 acc[4][4];
#pragma unroll
    for (int mt = 0; mt < 4; ++mt)
#pragma unroll
        for (int nt = 0; nt < 4; ++nt) acc[mt][nt] = (f32x4)0.0f;

    const char* Ap = (const char*)As;
    const char* Wp = (const char*)Ws;
#pragma unroll
    for (int ks = 0; ks < 4; ++ks) {
        int kb2 = ks * 64 + kg * 16;
        short8 af[4], bfr[4];
#pragma unroll
        for (int t = 0; t < 4; ++t) {
            int m = mbase + t * 16 + lr;
            af[t] = *(const short8*)(Ap + m * 256 + (kb2 ^ ((m & 15) << 4)));
            int n = nbase + t * 16 + lr;
            bfr[t] = *(const short8*)(Wp + n * 256 + (kb2 ^ ((n & 15) << 4)));
        }
#pragma unroll
        for (int mt = 0; mt < 4; ++mt)
#pragma unroll
            for (int nt = 0; nt < 4; ++nt)
                acc[mt][nt] = __builtin_amdgcn_mfma_f32_16x16x32_bf16(af[mt], bfr[nt], acc[mt][nt], 0, 0, 0);
    }

    float bv[4];
#pragma unroll
    for (int nt = 0; nt < 4; ++nt) bv[nt] = bias[nbase + nt * 16 + lr];
#pragma unroll
    for (int mt = 0; mt < 4; ++mt) {
#pragma unroll
        for (int r = 0; r < 4; ++r) {
            int gm = row0 + mbase + mt * 16 + kg * 4 + r;
            if (gm < N_NODES) {
#pragma unroll
                for (int nt = 0; nt < 4; ++nt) {
                    int gn = nbase + nt * 16 + lr;
                    float z = acc[mt][nt][r] + bv[nt];
                    z = (z >= 0.f) ? z : 0.2f * z;
                    float o = z + bf2f((u32)xres[(size_t)gm * D + gn]);
                    xbout[(size_t)gm * D + gn] = f2bf(o);
                }
            }
        }
    }
}

// ---------------- pooling + final BN + fc ----------------

__global__ void bounds_kernel(const int* __restrict__ batch, int* __restrict__ gs, int* __restrict__ ge) {
    for (int i = blockIdx.x * blockDim.x + threadIdx.x; i < N_NODES; i += gridDim.x * blockDim.x) {
        int b = batch[i];
        atomicMin(&gs[b], i);
        atomicMax(&ge[b], i + 1);
    }
}

__global__ void pool_kernel(const u16* __restrict__ xb, const int* __restrict__ gs,
                            const int* __restrict__ ge, float* __restrict__ pooled) {
    int g = blockIdx.x, f = threadIdx.x;
    int s = gs[g], e = ge[g];
    float a0 = 0.f, a1 = 0.f, a2 = 0.f, a3 = 0.f;
    int i = s;
    for (; i + 4 <= e; i += 4) {
        a0 += bf2f((u32)xb[(size_t)i * D + f]);
        a1 += bf2f((u32)xb[(size_t)(i + 1) * D + f]);
        a2 += bf2f((u32)xb[(size_t)(i + 2) * D + f]);
        a3 += bf2f((u32)xb[(size_t)(i + 3) * D + f]);
    }
    for (; i < e; ++i) a0 += bf2f((u32)xb[(size_t)i * D + f]);
    pooled[g * D + f] = (a0 + a1) + (a2 + a3);
}

__global__ void pooled_bn(const float* __restrict__ pooled, const float* __restrict__ g,
                          const float* __restrict__ b, float* __restrict__ pscale,
                          float* __restrict__ pshift) {
    int c = threadIdx.x;
    float s = 0.f, q = 0.f;
    for (int gi = 0; gi < N_GRAPHS; ++gi) {
        float v = pooled[gi * D + c];
        s += v; q += v * v;
    }
    float m = s / N_GRAPHS;
    float var = q / N_GRAPHS - m * m;
    var = fmaxf(var, 0.f);
    float sc = g[c] * rsqrtf(var + EPS);
    pscale[c] = sc;
    pshift[c] = b[c] - m * sc;
}

__global__ void out_kernel(const float* __restrict__ pooled, const float* __restrict__ pscale,
                           const float* __restrict__ pshift, const float* __restrict__ fcW,
                           const float* __restrict__ fcb, float* __restrict__ out) {
    int idx = blockIdx.x * blockDim.x + threadIdx.x;
    if (idx >= N_GRAPHS * LATENT) return;
    int g = idx >> 6, j = idx & 63;
    float acc = fcb[j];
    for (int c = 0; c < D; ++c) {
        float pv = pooled[g * D + c] * pscale[c] + pshift[c];
        acc += pv * fcW[c * LATENT + j];
    }
    out[idx] = acc;
}

// ---------------- launch ----------------

extern "C" void kernel_launch(void* const* d_in, const int* in_sizes, int n_in,
                              void* d_out, int out_size, void* d_ws, size_t ws_size,
                              hipStream_t stream) {
    const float* x_in = (const float*)d_in[0];
    const int* edges  = (const int*)d_in[1];
    const int* batch  = (const int*)d_in[2];
    const float* W1   = (const float*)d_in[3];
    const float* b1   = (const float*)d_in[4];
    const float* g1   = (const float*)d_in[5];
    const float* bt1  = (const float*)d_in[6];
    const float* W2   = (const float*)d_in[7];
    const float* b2   = (const float*)d_in[8];
    const float* bng  = (const float*)d_in[9];
    const float* bnb  = (const float*)d_in[10];
    const float* fcW  = (const float*)d_in[11];
    const float* fcb  = (const float*)d_in[12];
    float* out = (float*)d_out;
    const int* srcp = edges;
    const int* dstp = edges + N_EDGES;

    char* p = (char*)d_ws;
    auto alloc = [&](size_t bytes) -> char* {
        char* r = p;
        p += (bytes + 511) & ~(size_t)511;
        return r;
    };
    u16*   XB      = (u16*)alloc((size_t)N_NODES * D * 2);     // bf16 x stream (residual+gather)
    u16*   AB      = (u16*)alloc((size_t)N_NODES * D * 2);     // agg out -> H (in place)
    int*   csr     = (int*)alloc((size_t)N_EDGES * 4);
    int*   ebs     = (int*)alloc((size_t)N_EDGES * 4);
    int*   ebd     = (int*)alloc((size_t)N_EDGES * 4);
    int*   deg     = (int*)alloc((size_t)N_NODES * 4);
    int*   offsets = (int*)alloc((size_t)(N_NODES + 1) * 4);
    int*   bsum    = (int*)alloc((size_t)NB * 4);
    int*   boff    = (int*)alloc((size_t)NB * 4);
    int*   bhist   = (int*)alloc((size_t)NBUCK * 4);
    int*   bstart  = (int*)alloc((size_t)(NBUCK + 1) * 4);
    int*   gbcur   = (int*)alloc((size_t)NBUCK * 4);
    u16*   Wtb     = (u16*)alloc((size_t)6 * D * D * 2);       // bf16 transposed weights
    float* colsumA = (float*)alloc((size_t)6 * 256 * 4);       // [l]: sum@l*256, sq@l*256+128
    int*   counters= (int*)alloc(3 * 4);
    float* scalev  = (float*)alloc(D * 4);
    float* shiftv  = (float*)alloc(D * 4);
    int*   gs      = (int*)alloc(N_GRAPHS * 4);
    int*   ge      = (int*)alloc(N_GRAPHS * 4);
    float* pooled  = (float*)alloc((size_t)N_GRAPHS * D * 4);
    float* pscale  = (float*)alloc(D * 4);
    float* pshift  = (float*)alloc(D * 4);

    init_misc<<<7 + CONVX_BLOCKS, 256, 0, stream>>>(W1, W2, Wtb, x_in, XB, colsumA,
                                                    counters, bhist, gs, ge);

    const int EGRID = (N_EDGES + 4095) / 4096;   // 391
    bucket_hist<<<EGRID, 256, 0, stream>>>(dstp, bhist);
    bucket_scan<<<1, 256, 0, stream>>>(bhist, bstart, gbcur);
    bucket_scatter<<<EGRID, 256, 0, stream>>>(srcp, dstp, gbcur, ebs, ebd);
    hist_local<<<NBUCK, 256, 0, stream>>>(ebd, bstart, deg);
    scan_block_sum<<<NB, 256, 0, stream>>>(deg, bsum);
    scan_top<<<1, 512, 0, stream>>>(bsum, boff);
    scan_apply<<<NB, 256, 0, stream>>>(deg, boff, offsets);
    csr_fill_local<<<NBUCK, 256, 0, stream>>>(ebs, ebd, bstart, offsets, csr);

    const int GEMM_GRID = (N_NODES + 127) / 128;      // 782
    const int AGG_GRID = (N_NODES * 16 + 255) / 256;  // 6250
    for (int l = 0; l < 3; ++l) {
        agg_kernel<<<AGG_GRID, 256, 0, stream>>>(XB, csr, offsets, AB);
        gemm1_mfma<<<GEMM_GRID, 256, 0, stream>>>(AB, Wtb + (size_t)l * D * D, b1 + l * D,
                                                  colsumA + l * 256, colsumA + l * 256 + 128,
                                                  g1 + l * D, bt1 + l * D, scalev, shiftv,
                                                  counters + l);
        gemm2_mfma<<<GEMM_GRID, 256, 0, stream>>>(AB, Wtb + (size_t)(3 + l) * D * D, b2 + l * D,
                                                  scalev, shiftv, XB, XB);
    }

    bounds_kernel<<<256, 256, 0, stream>>>(batch, gs, ge);
    pool_kernel<<<N_GRAPHS, D, 0, stream>>>(XB, gs, ge, pooled);
    pooled_bn<<<1, D, 0, stream>>>(pooled, bng, bnb, pscale, pshift);
    out_kernel<<<(N_GRAPHS * LATENT + 255) / 256, 256, 0, stream>>>(pooled, pscale, pshift,
                                                                    fcW, fcb, out);
}

// Round 7
// 567.101 us; speedup vs baseline: 1.2114x; 1.2114x over previous
//
#include <hip/hip_runtime.h>

#define N_NODES 100000
#define N_EDGES 1600000
#define N_GRAPHS 1000
#define D 128
#define LATENT 64
#define EPS 1e-5f
#define NB ((N_NODES + 255) / 256)   // 391
#define NBUCK 196                    // buckets of 512 nodes: bucket = dst >> 9
#define BSH 9
#define CONVX_BLOCKS ((N_NODES * D / 4 + 255) / 256)   // 12500

typedef unsigned short u16;
typedef unsigned int u32;
typedef __attribute__((ext_vector_type(8))) short short8;   // 8 bf16 = 4 VGPR (MFMA A/B frag)
typedef __attribute__((ext_vector_type(4))) float f32x4;    // MFMA C/D frag

__device__ __forceinline__ float bf2f(u32 u) {
    union { u32 i; float f; } c; c.i = u << 16; return c.f;
}
__device__ __forceinline__ u16 f2bf(float f) {
    union { float f; u32 u; } c; c.f = f;
    u32 u = c.u;
    return (u16)((u + 0x7fffu + ((u >> 16) & 1u)) >> 16);   // RNE
}

// ---------------- fused init: weight convert + x convert + zero small bufs ----------------

__global__ void init_misc(const float* __restrict__ W1, const float* __restrict__ W2,
                          u16* __restrict__ Wt, const float* __restrict__ x,
                          u16* __restrict__ xb, float* __restrict__ colsumAll,
                          int* __restrict__ bhist,
                          int* __restrict__ gs, int* __restrict__ ge) {
    int b = blockIdx.x, t = threadIdx.x;
    if (b < 6) {
        const float* src = (b < 3) ? (W1 + (size_t)b * D * D) : (W2 + (size_t)(b - 3) * D * D);
        u16* dst = Wt + (size_t)b * D * D;
        for (int i = t; i < D * D; i += 256) {
            int k = i >> 7, n = i & 127;
            dst[n * D + k] = f2bf(src[i]);
        }
    } else if (b == 6) {
        for (int i = t; i < 6 * 256; i += 256) colsumAll[i] = 0.f;
        if (t < NBUCK) bhist[t] = 0;
        for (int i = t; i < N_GRAPHS; i += 256) { gs[i] = 0x7fffffff; ge[i] = 0; }
    } else {
        int idx = (b - 7) * 256 + t;
        if (idx < N_NODES * D / 4) {
            float4 v = *(const float4*)&x[(size_t)idx * 4];
            u32 lo = (u32)f2bf(v.x) | ((u32)f2bf(v.y) << 16);
            u32 hi = (u32)f2bf(v.z) | ((u32)f2bf(v.w) << 16);
            *(uint2*)&xb[(size_t)idx * 4] = make_uint2(lo, hi);
        }
    }
}

// ---------------- bucketed CSR build ----------------

__global__ void bucket_hist(const int* __restrict__ dst, int* __restrict__ bhist) {
    __shared__ int cnt[256];
    int t = threadIdx.x;
    cnt[t] = 0;
    __syncthreads();
    int base = blockIdx.x * 4096 + t * 16;
#pragma unroll
    for (int i = 0; i < 16; ++i) {
        int e = base + i;
        if (e < N_EDGES) atomicAdd(&cnt[dst[e] >> BSH], 1);
    }
    __syncthreads();
    if (t < NBUCK && cnt[t] > 0) atomicAdd(&bhist[t], cnt[t]);
}

__global__ void bucket_scan(const int* __restrict__ bhist, int* __restrict__ bstart,
                            int* __restrict__ gbcur) {
    __shared__ int s[256];
    int t = threadIdx.x;
    int v = (t < NBUCK) ? bhist[t] : 0;
    s[t] = v;
    __syncthreads();
    for (int off = 1; off < 256; off <<= 1) {
        int a = (t >= off) ? s[t - off] : 0;
        __syncthreads();
        s[t] += a;
        __syncthreads();
    }
    if (t < NBUCK) { int ex = s[t] - v; bstart[t] = ex; gbcur[t] = ex; }
    if (t == NBUCK - 1) bstart[NBUCK] = s[t];
}

__global__ __launch_bounds__(256)
void bucket_scatter(const int* __restrict__ src, const int* __restrict__ dst,
                    int* __restrict__ gbcur, int* __restrict__ ebs, int* __restrict__ ebd) {
    __shared__ int cnt[256], loff[256], basev[256], scn[256];
    __shared__ int psrc[4096], pdst[4096];
    __shared__ unsigned char pbkt[4096];
    int t = threadIdx.x;
    cnt[t] = 0;
    __syncthreads();
    int ebase = blockIdx.x * 4096;
    int d[16], sv[16], b[16], r[16];
#pragma unroll
    for (int i = 0; i < 16; ++i) {
        int e = ebase + t * 16 + i;
        bool ok = e < N_EDGES;
        d[i] = ok ? dst[e] : 0;
        sv[i] = ok ? src[e] : 0;
        b[i] = ok ? (d[i] >> BSH) : -1;
    }
#pragma unroll
    for (int i = 0; i < 16; ++i)
        r[i] = (b[i] >= 0) ? atomicAdd(&cnt[b[i]], 1) : 0;
    __syncthreads();
    int c = cnt[t];
    scn[t] = c;
    __syncthreads();
    for (int off = 1; off < 256; off <<= 1) {
        int a = (t >= off) ? scn[t - off] : 0;
        __syncthreads();
        scn[t] += a;
        __syncthreads();
    }
    loff[t] = scn[t] - c;
    if (c > 0) basev[t] = atomicAdd(&gbcur[t], c);
    __syncthreads();
#pragma unroll
    for (int i = 0; i < 16; ++i) {
        if (b[i] >= 0) {
            int p = loff[b[i]] + r[i];
            psrc[p] = sv[i];
            pdst[p] = d[i];
            pbkt[p] = (unsigned char)b[i];
        }
    }
    __syncthreads();
    int total = min(4096, N_EDGES - ebase);
    for (int i = t; i < total; i += 256) {
        int bb = pbkt[i];
        int g = basev[bb] + (i - loff[bb]);
        ebs[g] = psrc[i];
        ebd[g] = pdst[i];
    }
}

__global__ void hist_local(const int* __restrict__ ebd, const int* __restrict__ bstart,
                           int* __restrict__ deg) {
    __shared__ int h[512];
    int b = blockIdx.x, t = threadIdx.x;
    int nbase = b << BSH;
    h[t] = 0; h[t + 256] = 0;
    __syncthreads();
    int e0 = bstart[b], e1 = bstart[b + 1];
    for (int e = e0 + t; e < e1; e += 256)
        atomicAdd(&h[ebd[e] - nbase], 1);
    __syncthreads();
    int nlen = min(512, N_NODES - nbase);
    if (t < nlen) deg[nbase + t] = h[t];
    if (t + 256 < nlen) deg[nbase + t + 256] = h[t + 256];
}

__global__ void scan_block_sum(const int* __restrict__ deg, int* __restrict__ bsum) {
    __shared__ int s[256];
    int t = threadIdx.x;
    int i = blockIdx.x * 256 + t;
    s[t] = (i < N_NODES) ? deg[i] : 0;
    __syncthreads();
    for (int off = 128; off > 0; off >>= 1) {
        if (t < off) s[t] += s[t + off];
        __syncthreads();
    }
    if (t == 0) bsum[blockIdx.x] = s[0];
}

__global__ void scan_top(const int* __restrict__ bsum, int* __restrict__ boff) {
    __shared__ int s[512];
    int t = threadIdx.x;
    int v = (t < NB) ? bsum[t] : 0;
    s[t] = v;
    __syncthreads();
    for (int off = 1; off < 512; off <<= 1) {
        int add = (t >= off) ? s[t - off] : 0;
        __syncthreads();
        s[t] += add;
        __syncthreads();
    }
    if (t < NB) boff[t] = s[t] - v;
}

__global__ void scan_apply(const int* __restrict__ deg, const int* __restrict__ boff,
                           int* __restrict__ offsets) {
    __shared__ int s[256];
    int t = threadIdx.x;
    int i = blockIdx.x * 256 + t;
    int v = (i < N_NODES) ? deg[i] : 0;
    s[t] = v;
    __syncthreads();
    for (int off = 1; off < 256; off <<= 1) {
        int add = (t >= off) ? s[t - off] : 0;
        __syncthreads();
        s[t] += add;
        __syncthreads();
    }
    int base = boff[blockIdx.x];
    if (i < N_NODES) offsets[i] = base + s[t] - v;
    if (i == N_NODES - 1) offsets[N_NODES] = base + s[t];
}

__global__ void csr_fill_local(const int* __restrict__ ebs, const int* __restrict__ ebd,
                               const int* __restrict__ bstart, const int* __restrict__ offsets,
                               int* __restrict__ csr) {
    __shared__ int cur[512];
    int b = blockIdx.x, t = threadIdx.x;
    int nbase = b << BSH;
    int nlen = min(512, N_NODES - nbase);
    if (t < nlen) cur[t] = offsets[nbase + t];
    if (t + 256 < nlen) cur[t + 256] = offsets[nbase + t + 256];
    __syncthreads();
    int e0 = bstart[b], e1 = bstart[b + 1];
    for (int e = e0 + t; e < e1; e += 256) {
        int p = atomicAdd(&cur[ebd[e] - nbase], 1);
        csr[p] = ebs[e];
    }
}

// ---------------- aggregation: ab = bf16( x + sum_{j->i} x_j ), x in bf16 ----------------
// 16 lanes/node, uint4 (8 bf16) per lane, 8-deep load batch -> 128B in flight/thread.

__device__ __forceinline__ void acc8(float* a, uint4 v) {
    a[0] += bf2f(v.x & 0xffff); a[1] += bf2f(v.x >> 16);
    a[2] += bf2f(v.y & 0xffff); a[3] += bf2f(v.y >> 16);
    a[4] += bf2f(v.z & 0xffff); a[5] += bf2f(v.z >> 16);
    a[6] += bf2f(v.w & 0xffff); a[7] += bf2f(v.w >> 16);
}

__global__ void agg_kernel(const u16* __restrict__ xb, const int* __restrict__ csr,
                           const int* __restrict__ offsets, u16* __restrict__ ab) {
    int t = blockIdx.x * blockDim.x + threadIdx.x;
    int node = t >> 4;
    if (node >= N_NODES) return;
    int lane = t & 15;
    const uint4* xp = (const uint4*)(xb + lane * 8);   // advance: 16 uint4 per row
    float a[8] = {0, 0, 0, 0, 0, 0, 0, 0};
    acc8(a, xp[(size_t)node * 16]);
    int s = offsets[node], e = offsets[node + 1];
    int p = s;
    for (; p + 8 <= e; p += 8) {
        int j0 = csr[p], j1 = csr[p + 1], j2 = csr[p + 2], j3 = csr[p + 3];
        int j4 = csr[p + 4], j5 = csr[p + 5], j6 = csr[p + 6], j7 = csr[p + 7];
        uint4 v0 = xp[(size_t)j0 * 16];
        uint4 v1 = xp[(size_t)j1 * 16];
        uint4 v2 = xp[(size_t)j2 * 16];
        uint4 v3 = xp[(size_t)j3 * 16];
        uint4 v4 = xp[(size_t)j4 * 16];
        uint4 v5 = xp[(size_t)j5 * 16];
        uint4 v6 = xp[(size_t)j6 * 16];
        uint4 v7 = xp[(size_t)j7 * 16];
        acc8(a, v0); acc8(a, v1); acc8(a, v2); acc8(a, v3);
        acc8(a, v4); acc8(a, v5); acc8(a, v6); acc8(a, v7);
    }
    for (; p + 4 <= e; p += 4) {
        int j0 = csr[p], j1 = csr[p + 1], j2 = csr[p + 2], j3 = csr[p + 3];
        uint4 v0 = xp[(size_t)j0 * 16];
        uint4 v1 = xp[(size_t)j1 * 16];
        uint4 v2 = xp[(size_t)j2 * 16];
        uint4 v3 = xp[(size_t)j3 * 16];
        acc8(a, v0); acc8(a, v1); acc8(a, v2); acc8(a, v3);
    }
    for (; p < e; ++p)
        acc8(a, xp[(size_t)csr[p] * 16]);
    uint4 o;
    o.x = (u32)f2bf(a[0]) | ((u32)f2bf(a[1]) << 16);
    o.y = (u32)f2bf(a[2]) | ((u32)f2bf(a[3]) << 16);
    o.z = (u32)f2bf(a[4]) | ((u32)f2bf(a[5]) << 16);
    o.w = (u32)f2bf(a[6]) | ((u32)f2bf(a[7]) << 16);
    *(uint4*)&ab[(size_t)node * D + lane * 8] = o;
}

// ---------------- MFMA GEMM common geometry ----------------
// 256 thr = 4 waves, BM=128, N=128, K=128. Wave (wid): rows (wid>>1)*64, cols (wid&1)*64.
// LDS [row][k] bf16, 256B rows, XOR-swizzle byte ^= ((row&15)<<4).

// GEMM1: H = leaky(A@W1 + b1) bf16 IN PLACE over A; fused BN column stats.
__global__ __launch_bounds__(256, 2)
void gemm1_mfma(u16* __restrict__ AB, const u16* __restrict__ Wt,
                const float* __restrict__ bias,
                float* __restrict__ colsum, float* __restrict__ colsq) {
    __shared__ u16 As[128 * 128];
    __shared__ u16 Ws[128 * 128];
    __shared__ float csumL[D], csqL[D];
    int tid = threadIdx.x;
    int row0 = blockIdx.x * 128;

    if (tid < D) { csumL[tid] = 0.f; csqL[tid] = 0.f; }
    const uint4* Wg = (const uint4*)Wt;
#pragma unroll
    for (int i = 0; i < 8; ++i) {
        int q = i * 256 + tid;
        int m = q >> 4, kc = q & 15;
        uint4 wv = Wg[q];
        *(uint4*)((char*)Ws + m * 256 + ((kc * 16) ^ ((m & 15) << 4))) = wv;
        uint4 av = make_uint4(0, 0, 0, 0);
        int gm = row0 + m;
        if (gm < N_NODES) av = *(const uint4*)&AB[(size_t)gm * D + kc * 8];
        *(uint4*)((char*)As + m * 256 + ((kc * 16) ^ ((m & 15) << 4))) = av;
    }
    __syncthreads();

    int lane = tid & 63;
    int wid = tid >> 6;
    int mbase = (wid >> 1) * 64, nbase = (wid & 1) * 64;
    int lr = lane & 15, kg = lane >> 4;
    f32x4 acc[4][4];
#pragma unroll
    for (int mt = 0; mt < 4; ++mt)
#pragma unroll
        for (int nt = 0; nt < 4; ++nt) acc[mt][nt] = (f32x4)0.0f;

    const char* Ap = (const char*)As;
    const char* Wp = (const char*)Ws;
#pragma unroll
    for (int ks = 0; ks < 4; ++ks) {
        int kb2 = ks * 64 + kg * 16;
        short8 af[4], bfr[4];
#pragma unroll
        for (int t = 0; t < 4; ++t) {
            int m = mbase + t * 16 + lr;
            af[t] = *(const short8*)(Ap + m * 256 + (kb2 ^ ((m & 15) << 4)));
            int n = nbase + t * 16 + lr;
            bfr[t] = *(const short8*)(Wp + n * 256 + (kb2 ^ ((n & 15) << 4)));
        }
#pragma unroll
        for (int mt = 0; mt < 4; ++mt)
#pragma unroll
            for (int nt = 0; nt < 4; ++nt)
                acc[mt][nt] = __builtin_amdgcn_mfma_f32_16x16x32_bf16(af[mt], bfr[nt], acc[mt][nt], 0, 0, 0);
    }

    float bv[4], ls[4] = {0, 0, 0, 0}, lq[4] = {0, 0, 0, 0};
#pragma unroll
    for (int nt = 0; nt < 4; ++nt) bv[nt] = bias[nbase + nt * 16 + lr];
#pragma unroll
    for (int mt = 0; mt < 4; ++mt) {
#pragma unroll
        for (int r = 0; r < 4; ++r) {
            int gm = row0 + mbase + mt * 16 + kg * 4 + r;
            if (gm < N_NODES) {
#pragma unroll
                for (int nt = 0; nt < 4; ++nt) {
                    float z = acc[mt][nt][r] + bv[nt];
                    z = (z >= 0.f) ? z : 0.2f * z;
                    AB[(size_t)gm * D + nbase + nt * 16 + lr] = f2bf(z);
                    ls[nt] += z; lq[nt] += z * z;
                }
            }
        }
    }
#pragma unroll
    for (int nt = 0; nt < 4; ++nt) {
        ls[nt] += __shfl_down(ls[nt], 32); ls[nt] += __shfl_down(ls[nt], 16);
        lq[nt] += __shfl_down(lq[nt], 32); lq[nt] += __shfl_down(lq[nt], 16);
    }
    if (lane < 16) {
#pragma unroll
        for (int nt = 0; nt < 4; ++nt) {
            atomicAdd(&csumL[nbase + nt * 16 + lane], ls[nt]);
            atomicAdd(&csqL[nbase + nt * 16 + lane], lq[nt]);
        }
    }
    __syncthreads();
    if (tid < D) {
        atomicAdd(&colsum[tid], csumL[tid]);
        atomicAdd(&colsq[tid], csqL[tid]);
    }
}

// ---------------- BN finalize (tiny kernel; cross-XCD handoff via kernel boundary) ----------------

__global__ void bn_fin(const float* __restrict__ colsum, const float* __restrict__ colsq,
                       const float* __restrict__ g, const float* __restrict__ bt,
                       float* __restrict__ scale, float* __restrict__ shift) {
    int c = threadIdx.x;
    float m = colsum[c] * (1.0f / N_NODES);
    float var = fmaxf(colsq[c] * (1.0f / N_NODES) - m * m, 0.f);
    float sc = g[c] * rsqrtf(var + EPS);
    scale[c] = sc;
    shift[c] = bt[c] - m * sc;
}

// GEMM2: x = bf16( leaky(BN(H)@W2 + b2) + xres ), all-bf16 residual stream.
__global__ __launch_bounds__(256, 2)
void gemm2_mfma(const u16* __restrict__ HB, const u16* __restrict__ Wt,
                const float* __restrict__ bias, const float* __restrict__ scalev,
                const float* __restrict__ shiftv, const u16* __restrict__ xres,
                u16* __restrict__ xbout) {
    __shared__ u16 As[128 * 128];
    __shared__ u16 Ws[128 * 128];
    int tid = threadIdx.x;
    int row0 = blockIdx.x * 128;

    const uint4* Wg = (const uint4*)Wt;
#pragma unroll
    for (int i = 0; i < 8; ++i) {
        int q = i * 256 + tid;
        int m = q >> 4, kc = q & 15;
        uint4 wv = Wg[q];
        *(uint4*)((char*)Ws + m * 256 + ((kc * 16) ^ ((m & 15) << 4))) = wv;
        uint4 av = make_uint4(0, 0, 0, 0);
        int gm = row0 + m;
        if (gm < N_NODES) {
            uint4 h = *(const uint4*)&HB[(size_t)gm * D + kc * 8];
            float4 s0 = *(const float4*)&scalev[kc * 8];
            float4 s1 = *(const float4*)&scalev[kc * 8 + 4];
            float4 t0 = *(const float4*)&shiftv[kc * 8];
            float4 t1 = *(const float4*)&shiftv[kc * 8 + 4];
            float f0 = bf2f(h.x & 0xffff) * s0.x + t0.x;
            float f1 = bf2f(h.x >> 16)    * s0.y + t0.y;
            float f2 = bf2f(h.y & 0xffff) * s0.z + t0.z;
            float f3 = bf2f(h.y >> 16)    * s0.w + t0.w;
            float f4 = bf2f(h.z & 0xffff) * s1.x + t1.x;
            float f5 = bf2f(h.z >> 16)    * s1.y + t1.y;
            float f6 = bf2f(h.w & 0xffff) * s1.z + t1.z;
            float f7 = bf2f(h.w >> 16)    * s1.w + t1.w;
            av.x = (u32)f2bf(f0) | ((u32)f2bf(f1) << 16);
            av.y = (u32)f2bf(f2) | ((u32)f2bf(f3) << 16);
            av.z = (u32)f2bf(f4) | ((u32)f2bf(f5) << 16);
            av.w = (u32)f2bf(f6) | ((u32)f2bf(f7) << 16);
        }
        *(uint4*)((char*)As + m * 256 + ((kc * 16) ^ ((m & 15) << 4))) = av;
    }
    __syncthreads();

    int lane = tid & 63;
    int wid = tid >> 6;
    int mbase = (wid >> 1) * 64, nbase = (wid & 1) * 64;
    int lr = lane & 15, kg = lane >> 4;
    f32x4 acc[4][4];
#pragma unroll
    for (int mt = 0; mt < 4; ++mt)
#pragma unroll
        for (int nt = 0; nt < 4; ++nt) acc[mt][nt] = (f32x4)0.0f;

    const char* Ap = (const char*)As;
    const char* Wp = (const char*)Ws;
#pragma unroll
    for (int ks = 0; ks < 4; ++ks) {
        int kb2 = ks * 64 + kg * 16;
        short8 af[4], bfr[4];
#pragma unroll
        for (int t = 0; t < 4; ++t) {
            int m = mbase + t * 16 + lr;
            af[t] = *(const short8*)(Ap + m * 256 + (kb2 ^ ((m & 15) << 4)));
            int n = nbase + t * 16 + lr;
            bfr[t] = *(const short8*)(Wp + n * 256 + (kb2 ^ ((n & 15) << 4)));
        }
#pragma unroll
        for (int mt = 0; mt < 4; ++mt)
#pragma unroll
            for (int nt = 0; nt < 4; ++nt)
                acc[mt][nt] = __builtin_amdgcn_mfma_f32_16x16x32_bf16(af[mt], bfr[nt], acc[mt][nt], 0, 0, 0);
    }

    float bv[4];
#pragma unroll
    for (int nt = 0; nt < 4; ++nt) bv[nt] = bias[nbase + nt * 16 + lr];
#pragma unroll
    for (int mt = 0; mt < 4; ++mt) {
#pragma unroll
        for (int r = 0; r < 4; ++r) {
            int gm = row0 + mbase + mt * 16 + kg * 4 + r;
            if (gm < N_NODES) {
#pragma unroll
                for (int nt = 0; nt < 4; ++nt) {
                    int gn = nbase + nt * 16 + lr;
                    float z = acc[mt][nt][r] + bv[nt];
                    z = (z >= 0.f) ? z : 0.2f * z;
                    float o = z + bf2f((u32)xres[(size_t)gm * D + gn]);
                    xbout[(size_t)gm * D + gn] = f2bf(o);
                }
            }
        }
    }
}

// ---------------- pooling + final BN + fc ----------------

__global__ void bounds_kernel(const int* __restrict__ batch, int* __restrict__ gs, int* __restrict__ ge) {
    for (int i = blockIdx.x * blockDim.x + threadIdx.x; i < N_NODES; i += gridDim.x * blockDim.x) {
        int b = batch[i];
        atomicMin(&gs[b], i);
        atomicMax(&ge[b], i + 1);
    }
}

__global__ void pool_kernel(const u16* __restrict__ xb, const int* __restrict__ gs,
                            const int* __restrict__ ge, float* __restrict__ pooled) {
    int g = blockIdx.x, f = threadIdx.x;
    int s = gs[g], e = ge[g];
    float a0 = 0.f, a1 = 0.f, a2 = 0.f, a3 = 0.f;
    int i = s;
    for (; i + 4 <= e; i += 4) {
        a0 += bf2f((u32)xb[(size_t)i * D + f]);
        a1 += bf2f((u32)xb[(size_t)(i + 1) * D + f]);
        a2 += bf2f((u32)xb[(size_t)(i + 2) * D + f]);
        a3 += bf2f((u32)xb[(size_t)(i + 3) * D + f]);
    }
    for (; i < e; ++i) a0 += bf2f((u32)xb[(size_t)i * D + f]);
    pooled[g * D + f] = (a0 + a1) + (a2 + a3);
}

__global__ void pooled_bn(const float* __restrict__ pooled, const float* __restrict__ g,
                          const float* __restrict__ b, float* __restrict__ pscale,
                          float* __restrict__ pshift) {
    int c = threadIdx.x;
    float s = 0.f, q = 0.f;
    for (int gi = 0; gi < N_GRAPHS; ++gi) {
        float v = pooled[gi * D + c];
        s += v; q += v * v;
    }
    float m = s / N_GRAPHS;
    float var = q / N_GRAPHS - m * m;
    var = fmaxf(var, 0.f);
    float sc = g[c] * rsqrtf(var + EPS);
    pscale[c] = sc;
    pshift[c] = b[c] - m * sc;
}

__global__ void out_kernel(const float* __restrict__ pooled, const float* __restrict__ pscale,
                           const float* __restrict__ pshift, const float* __restrict__ fcW,
                           const float* __restrict__ fcb, float* __restrict__ out) {
    int idx = blockIdx.x * blockDim.x + threadIdx.x;
    if (idx >= N_GRAPHS * LATENT) return;
    int g = idx >> 6, j = idx & 63;
    float acc = fcb[j];
    for (int c = 0; c < D; ++c) {
        float pv = pooled[g * D + c] * pscale[c] + pshift[c];
        acc += pv * fcW[c * LATENT + j];
    }
    out[idx] = acc;
}

// ---------------- launch ----------------

extern "C" void kernel_launch(void* const* d_in, const int* in_sizes, int n_in,
                              void* d_out, int out_size, void* d_ws, size_t ws_size,
                              hipStream_t stream) {
    const float* x_in = (const float*)d_in[0];
    const int* edges  = (const int*)d_in[1];
    const int* batch  = (const int*)d_in[2];
    const float* W1   = (const float*)d_in[3];
    const float* b1   = (const float*)d_in[4];
    const float* g1   = (const float*)d_in[5];
    const float* bt1  = (const float*)d_in[6];
    const float* W2   = (const float*)d_in[7];
    const float* b2   = (const float*)d_in[8];
    const float* bng  = (const float*)d_in[9];
    const float* bnb  = (const float*)d_in[10];
    const float* fcW  = (const float*)d_in[11];
    const float* fcb  = (const float*)d_in[12];
    float* out = (float*)d_out;
    const int* srcp = edges;
    const int* dstp = edges + N_EDGES;

    char* p = (char*)d_ws;
    auto alloc = [&](size_t bytes) -> char* {
        char* r = p;
        p += (bytes + 511) & ~(size_t)511;
        return r;
    };
    u16*   XB      = (u16*)alloc((size_t)N_NODES * D * 2);     // bf16 x stream (residual+gather)
    u16*   AB      = (u16*)alloc((size_t)N_NODES * D * 2);     // agg out -> H (in place)
    int*   csr     = (int*)alloc((size_t)N_EDGES * 4);
    int*   ebs     = (int*)alloc((size_t)N_EDGES * 4);
    int*   ebd     = (int*)alloc((size_t)N_EDGES * 4);
    int*   deg     = (int*)alloc((size_t)N_NODES * 4);
    int*   offsets = (int*)alloc((size_t)(N_NODES + 1) * 4);
    int*   bsum    = (int*)alloc((size_t)NB * 4);
    int*   boff    = (int*)alloc((size_t)NB * 4);
    int*   bhist   = (int*)alloc((size_t)NBUCK * 4);
    int*   bstart  = (int*)alloc((size_t)(NBUCK + 1) * 4);
    int*   gbcur   = (int*)alloc((size_t)NBUCK * 4);
    u16*   Wtb     = (u16*)alloc((size_t)6 * D * D * 2);       // bf16 transposed weights
    float* colsumA = (float*)alloc((size_t)6 * 256 * 4);       // [l]: sum@l*256, sq@l*256+128
    float* scalev  = (float*)alloc(D * 4);
    float* shiftv  = (float*)alloc(D * 4);
    int*   gs      = (int*)alloc(N_GRAPHS * 4);
    int*   ge      = (int*)alloc(N_GRAPHS * 4);
    float* pooled  = (float*)alloc((size_t)N_GRAPHS * D * 4);
    float* pscale  = (float*)alloc(D * 4);
    float* pshift  = (float*)alloc(D * 4);

    init_misc<<<7 + CONVX_BLOCKS, 256, 0, stream>>>(W1, W2, Wtb, x_in, XB, colsumA,
                                                    bhist, gs, ge);

    const int EGRID = (N_EDGES + 4095) / 4096;   // 391
    bucket_hist<<<EGRID, 256, 0, stream>>>(dstp, bhist);
    bucket_scan<<<1, 256, 0, stream>>>(bhist, bstart, gbcur);
    bucket_scatter<<<EGRID, 256, 0, stream>>>(srcp, dstp, gbcur, ebs, ebd);
    hist_local<<<NBUCK, 256, 0, stream>>>(ebd, bstart, deg);
    scan_block_sum<<<NB, 256, 0, stream>>>(deg, bsum);
    scan_top<<<1, 512, 0, stream>>>(bsum, boff);
    scan_apply<<<NB, 256, 0, stream>>>(deg, boff, offsets);
    csr_fill_local<<<NBUCK, 256, 0, stream>>>(ebs, ebd, bstart, offsets, csr);

    const int GEMM_GRID = (N_NODES + 127) / 128;      // 782
    const int AGG_GRID = (N_NODES * 16 + 255) / 256;  // 6250
    for (int l = 0; l < 3; ++l) {
        agg_kernel<<<AGG_GRID, 256, 0, stream>>>(XB, csr, offsets, AB);
        gemm1_mfma<<<GEMM_GRID, 256, 0, stream>>>(AB, Wtb + (size_t)l * D * D, b1 + l * D,
                                                  colsumA + l * 256, colsumA + l * 256 + 128);
        bn_fin<<<1, D, 0, stream>>>(colsumA + l * 256, colsumA + l * 256 + 128,
                                    g1 + l * D, bt1 + l * D, scalev, shiftv);
        gemm2_mfma<<<GEMM_GRID, 256, 0, stream>>>(AB, Wtb + (size_t)(3 + l) * D * D, b2 + l * D,
                                                  scalev, shiftv, XB, XB);
    }

    bounds_kernel<<<256, 256, 0, stream>>>(batch, gs, ge);
    pool_kernel<<<N_GRAPHS, D, 0, stream>>>(XB, gs, ge, pooled);
    pooled_bn<<<1, D, 0, stream>>>(pooled, bng, bnb, pscale, pshift);
    out_kernel<<<(N_GRAPHS * LATENT + 255) / 256, 256, 0, stream>>>(pooled, pscale, pshift,
                                                                    fcW, fcb, out);
}

// Round 8
// 557.652 us; speedup vs baseline: 1.2319x; 1.0169x over previous
//
#include <hip/hip_runtime.h>

#define N_NODES 100000
#define N_EDGES 1600000
#define N_GRAPHS 1000
#define D 128
#define LATENT 64
#define EPS 1e-5f
#define NB ((N_NODES + 255) / 256)   // 391
#define NBUCK 196                    // buckets of 512 nodes: bucket = dst >> 9
#define BSH 9
#define CONVX_BLOCKS ((N_NODES * D / 4 + 255) / 256)   // 12500

typedef unsigned short u16;
typedef unsigned int u32;
typedef __attribute__((ext_vector_type(8))) short short8;   // 8 bf16 = 4 VGPR (MFMA A/B frag)
typedef __attribute__((ext_vector_type(4))) float f32x4;    // MFMA C/D frag

__device__ __forceinline__ float bf2f(u32 u) {
    union { u32 i; float f; } c; c.i = u << 16; return c.f;
}
__device__ __forceinline__ u16 f2bf(float f) {
    union { float f; u32 u; } c; c.f = f;
    u32 u = c.u;
    return (u16)((u + 0x7fffu + ((u >> 16) & 1u)) >> 16);   // RNE
}

// ---------------- fused init: weight convert + x convert + zero small bufs ----------------

__global__ void init_misc(const float* __restrict__ W1, const float* __restrict__ W2,
                          u16* __restrict__ Wt, const float* __restrict__ x,
                          u16* __restrict__ xb, float* __restrict__ colsumAll,
                          int* __restrict__ bhist,
                          int* __restrict__ gs, int* __restrict__ ge) {
    int b = blockIdx.x, t = threadIdx.x;
    if (b < 6) {
        const float* src = (b < 3) ? (W1 + (size_t)b * D * D) : (W2 + (size_t)(b - 3) * D * D);
        u16* dst = Wt + (size_t)b * D * D;
        for (int i = t; i < D * D; i += 256) {
            int k = i >> 7, n = i & 127;
            dst[n * D + k] = f2bf(src[i]);
        }
    } else if (b == 6) {
        for (int i = t; i < 6 * 256; i += 256) colsumAll[i] = 0.f;
        if (t < NBUCK) bhist[t] = 0;
        for (int i = t; i < N_GRAPHS; i += 256) { gs[i] = 0x7fffffff; ge[i] = 0; }
    } else {
        int idx = (b - 7) * 256 + t;
        if (idx < N_NODES * D / 4) {
            float4 v = *(const float4*)&x[(size_t)idx * 4];
            u32 lo = (u32)f2bf(v.x) | ((u32)f2bf(v.y) << 16);
            u32 hi = (u32)f2bf(v.z) | ((u32)f2bf(v.w) << 16);
            *(uint2*)&xb[(size_t)idx * 4] = make_uint2(lo, hi);
        }
    }
}

// ---------------- bucketed CSR build ----------------
// Edge staging packed: ebp = (src << 9) | (dst & 511); bucket = dst >> 9 implicit in range.

__global__ void bucket_hist(const int* __restrict__ dst, int* __restrict__ bhist) {
    __shared__ int cnt[256];
    int t = threadIdx.x;
    cnt[t] = 0;
    __syncthreads();
    int base = blockIdx.x * 4096 + t * 16;
#pragma unroll
    for (int i = 0; i < 16; ++i) {
        int e = base + i;
        if (e < N_EDGES) atomicAdd(&cnt[dst[e] >> BSH], 1);
    }
    __syncthreads();
    if (t < NBUCK && cnt[t] > 0) atomicAdd(&bhist[t], cnt[t]);
}

__global__ void bucket_scan(const int* __restrict__ bhist, int* __restrict__ bstart,
                            int* __restrict__ gbcur) {
    __shared__ int s[256];
    int t = threadIdx.x;
    int v = (t < NBUCK) ? bhist[t] : 0;
    s[t] = v;
    __syncthreads();
    for (int off = 1; off < 256; off <<= 1) {
        int a = (t >= off) ? s[t - off] : 0;
        __syncthreads();
        s[t] += a;
        __syncthreads();
    }
    if (t < NBUCK) { int ex = s[t] - v; bstart[t] = ex; gbcur[t] = ex; }
    if (t == NBUCK - 1) bstart[NBUCK] = s[t];
}

__global__ __launch_bounds__(256)
void bucket_scatter(const int* __restrict__ src, const int* __restrict__ dst,
                    int* __restrict__ gbcur, u32* __restrict__ ebp) {
    __shared__ int cnt[256], loff[256], basev[256], scn[256];
    __shared__ u32 pp[4096];
    __shared__ unsigned char pbkt[4096];
    int t = threadIdx.x;
    cnt[t] = 0;
    __syncthreads();
    int ebase = blockIdx.x * 4096;
    int b[16], r[16];
    u32 pk[16];
#pragma unroll
    for (int i = 0; i < 16; ++i) {
        int e = ebase + t * 16 + i;
        bool ok = e < N_EDGES;
        int d = ok ? dst[e] : 0;
        int sv = ok ? src[e] : 0;
        pk[i] = ((u32)sv << BSH) | (u32)(d & 511);
        b[i] = ok ? (d >> BSH) : -1;
    }
#pragma unroll
    for (int i = 0; i < 16; ++i)
        r[i] = (b[i] >= 0) ? atomicAdd(&cnt[b[i]], 1) : 0;
    __syncthreads();
    int c = cnt[t];
    scn[t] = c;
    __syncthreads();
    for (int off = 1; off < 256; off <<= 1) {
        int a = (t >= off) ? scn[t - off] : 0;
        __syncthreads();
        scn[t] += a;
        __syncthreads();
    }
    loff[t] = scn[t] - c;
    if (c > 0) basev[t] = atomicAdd(&gbcur[t], c);
    __syncthreads();
#pragma unroll
    for (int i = 0; i < 16; ++i) {
        if (b[i] >= 0) {
            int p = loff[b[i]] + r[i];
            pp[p] = pk[i];
            pbkt[p] = (unsigned char)b[i];
        }
    }
    __syncthreads();
    int total = min(4096, N_EDGES - ebase);
    for (int i = t; i < total; i += 256) {
        int bb = pbkt[i];
        int g = basev[bb] + (i - loff[bb]);
        ebp[g] = pp[i];
    }
}

__global__ void hist_local(const u32* __restrict__ ebp, const int* __restrict__ bstart,
                           int* __restrict__ deg) {
    __shared__ int h[512];
    int b = blockIdx.x, t = threadIdx.x;
    int nbase = b << BSH;
    h[t] = 0; h[t + 256] = 0;
    __syncthreads();
    int e0 = bstart[b], e1 = bstart[b + 1];
    for (int e = e0 + t; e < e1; e += 256)
        atomicAdd(&h[ebp[e] & 511], 1);
    __syncthreads();
    int nlen = min(512, N_NODES - nbase);
    if (t < nlen) deg[nbase + t] = h[t];
    if (t + 256 < nlen) deg[nbase + t + 256] = h[t + 256];
}

__global__ void scan_block_sum(const int* __restrict__ deg, int* __restrict__ bsum) {
    __shared__ int s[256];
    int t = threadIdx.x;
    int i = blockIdx.x * 256 + t;
    s[t] = (i < N_NODES) ? deg[i] : 0;
    __syncthreads();
    for (int off = 128; off > 0; off >>= 1) {
        if (t < off) s[t] += s[t + off];
        __syncthreads();
    }
    if (t == 0) bsum[blockIdx.x] = s[0];
}

__global__ void scan_top(const int* __restrict__ bsum, int* __restrict__ boff) {
    __shared__ int s[512];
    int t = threadIdx.x;
    int v = (t < NB) ? bsum[t] : 0;
    s[t] = v;
    __syncthreads();
    for (int off = 1; off < 512; off <<= 1) {
        int add = (t >= off) ? s[t - off] : 0;
        __syncthreads();
        s[t] += add;
        __syncthreads();
    }
    if (t < NB) boff[t] = s[t] - v;
}

__global__ void scan_apply(const int* __restrict__ deg, const int* __restrict__ boff,
                           int* __restrict__ offsets) {
    __shared__ int s[256];
    int t = threadIdx.x;
    int i = blockIdx.x * 256 + t;
    int v = (i < N_NODES) ? deg[i] : 0;
    s[t] = v;
    __syncthreads();
    for (int off = 1; off < 256; off <<= 1) {
        int add = (t >= off) ? s[t - off] : 0;
        __syncthreads();
        s[t] += add;
        __syncthreads();
    }
    int base = boff[blockIdx.x];
    if (i < N_NODES) offsets[i] = base + s[t] - v;
    if (i == N_NODES - 1) offsets[N_NODES] = base + s[t];
}

__global__ void csr_fill_local(const u32* __restrict__ ebp, const int* __restrict__ bstart,
                               const int* __restrict__ offsets, int* __restrict__ csr) {
    __shared__ int cur[512];
    int b = blockIdx.x, t = threadIdx.x;
    int nbase = b << BSH;
    int nlen = min(512, N_NODES - nbase);
    if (t < nlen) cur[t] = offsets[nbase + t];
    if (t + 256 < nlen) cur[t + 256] = offsets[nbase + t + 256];
    __syncthreads();
    int e0 = bstart[b], e1 = bstart[b + 1];
    for (int e = e0 + t; e < e1; e += 256) {
        u32 pk = ebp[e];
        int p = atomicAdd(&cur[pk & 511], 1);
        csr[p] = (int)(pk >> BSH);
    }
}

// ---------------- aggregation: ab = bf16( x + sum_{j->i} x_j ), x in bf16 ----------------
// 16 lanes/node, uint4 (8 bf16) per lane, 8-deep load batch -> 128B in flight/thread.

__device__ __forceinline__ void acc8(float* a, uint4 v) {
    a[0] += bf2f(v.x & 0xffff); a[1] += bf2f(v.x >> 16);
    a[2] += bf2f(v.y & 0xffff); a[3] += bf2f(v.y >> 16);
    a[4] += bf2f(v.z & 0xffff); a[5] += bf2f(v.z >> 16);
    a[6] += bf2f(v.w & 0xffff); a[7] += bf2f(v.w >> 16);
}

__global__ void agg_kernel(const u16* __restrict__ xb, const int* __restrict__ csr,
                           const int* __restrict__ offsets, u16* __restrict__ ab) {
    int t = blockIdx.x * blockDim.x + threadIdx.x;
    int node = t >> 4;
    if (node >= N_NODES) return;
    int lane = t & 15;
    const uint4* xp = (const uint4*)(xb + lane * 8);   // advance: 16 uint4 per row
    float a[8] = {0, 0, 0, 0, 0, 0, 0, 0};
    acc8(a, xp[(size_t)node * 16]);
    int s = offsets[node], e = offsets[node + 1];
    int p = s;
    for (; p + 8 <= e; p += 8) {
        int j0 = csr[p], j1 = csr[p + 1], j2 = csr[p + 2], j3 = csr[p + 3];
        int j4 = csr[p + 4], j5 = csr[p + 5], j6 = csr[p + 6], j7 = csr[p + 7];
        uint4 v0 = xp[(size_t)j0 * 16];
        uint4 v1 = xp[(size_t)j1 * 16];
        uint4 v2 = xp[(size_t)j2 * 16];
        uint4 v3 = xp[(size_t)j3 * 16];
        uint4 v4 = xp[(size_t)j4 * 16];
        uint4 v5 = xp[(size_t)j5 * 16];
        uint4 v6 = xp[(size_t)j6 * 16];
        uint4 v7 = xp[(size_t)j7 * 16];
        acc8(a, v0); acc8(a, v1); acc8(a, v2); acc8(a, v3);
        acc8(a, v4); acc8(a, v5); acc8(a, v6); acc8(a, v7);
    }
    for (; p + 4 <= e; p += 4) {
        int j0 = csr[p], j1 = csr[p + 1], j2 = csr[p + 2], j3 = csr[p + 3];
        uint4 v0 = xp[(size_t)j0 * 16];
        uint4 v1 = xp[(size_t)j1 * 16];
        uint4 v2 = xp[(size_t)j2 * 16];
        uint4 v3 = xp[(size_t)j3 * 16];
        acc8(a, v0); acc8(a, v1); acc8(a, v2); acc8(a, v3);
    }
    for (; p < e; ++p)
        acc8(a, xp[(size_t)csr[p] * 16]);
    uint4 o;
    o.x = (u32)f2bf(a[0]) | ((u32)f2bf(a[1]) << 16);
    o.y = (u32)f2bf(a[2]) | ((u32)f2bf(a[3]) << 16);
    o.z = (u32)f2bf(a[4]) | ((u32)f2bf(a[5]) << 16);
    o.w = (u32)f2bf(a[6]) | ((u32)f2bf(a[7]) << 16);
    *(uint4*)&ab[(size_t)node * D + lane * 8] = o;
}

// ---------------- MFMA GEMM common geometry ----------------
// 256 thr = 4 waves, BM=128, N=128, K=128. Wave (wid): rows (wid>>1)*64, cols (wid&1)*64.
// A staged in LDS (XOR-swizzle byte ^= ((row&15)<<4)); B frags read DIRECT from
// global Wt (32KB, L1/L2-resident) -> LDS ~33KB -> 4 blocks/CU.

// GEMM1: H = leaky(A@W1 + b1) bf16 IN PLACE over A; fused BN column stats.
__global__ __launch_bounds__(256, 4)
void gemm1_mfma(u16* __restrict__ AB, const u16* __restrict__ Wt,
                const float* __restrict__ bias,
                float* __restrict__ colsum, float* __restrict__ colsq) {
    __shared__ u16 As[128 * 128];
    __shared__ float csumL[D], csqL[D];
    int tid = threadIdx.x;
    int row0 = blockIdx.x * 128;

    if (tid < D) { csumL[tid] = 0.f; csqL[tid] = 0.f; }
#pragma unroll
    for (int i = 0; i < 8; ++i) {
        int q = i * 256 + tid;
        int m = q >> 4, kc = q & 15;
        uint4 av = make_uint4(0, 0, 0, 0);
        int gm = row0 + m;
        if (gm < N_NODES) av = *(const uint4*)&AB[(size_t)gm * D + kc * 8];
        *(uint4*)((char*)As + m * 256 + ((kc * 16) ^ ((m & 15) << 4))) = av;
    }
    __syncthreads();

    int lane = tid & 63;
    int wid = tid >> 6;
    int mbase = (wid >> 1) * 64, nbase = (wid & 1) * 64;
    int lr = lane & 15, kg = lane >> 4;
    f32x4 acc[4][4];
#pragma unroll
    for (int mt = 0; mt < 4; ++mt)
#pragma unroll
        for (int nt = 0; nt < 4; ++nt) acc[mt][nt] = (f32x4)0.0f;

    const char* Ap = (const char*)As;
#pragma unroll
    for (int ks = 0; ks < 4; ++ks) {
        int kb2 = ks * 64 + kg * 16;
        short8 af[4], bfr[4];
#pragma unroll
        for (int t = 0; t < 4; ++t) {
            int m = mbase + t * 16 + lr;
            af[t] = *(const short8*)(Ap + m * 256 + (kb2 ^ ((m & 15) << 4)));
            int n = nbase + t * 16 + lr;
            bfr[t] = *(const short8*)&Wt[n * D + ks * 32 + kg * 8];
        }
#pragma unroll
        for (int mt = 0; mt < 4; ++mt)
#pragma unroll
            for (int nt = 0; nt < 4; ++nt)
                acc[mt][nt] = __builtin_amdgcn_mfma_f32_16x16x32_bf16(af[mt], bfr[nt], acc[mt][nt], 0, 0, 0);
    }

    float bv[4], ls[4] = {0, 0, 0, 0}, lq[4] = {0, 0, 0, 0};
#pragma unroll
    for (int nt = 0; nt < 4; ++nt) bv[nt] = bias[nbase + nt * 16 + lr];
#pragma unroll
    for (int mt = 0; mt < 4; ++mt) {
#pragma unroll
        for (int r = 0; r < 4; ++r) {
            int gm = row0 + mbase + mt * 16 + kg * 4 + r;
            if (gm < N_NODES) {
#pragma unroll
                for (int nt = 0; nt < 4; ++nt) {
                    float z = acc[mt][nt][r] + bv[nt];
                    z = (z >= 0.f) ? z : 0.2f * z;
                    AB[(size_t)gm * D + nbase + nt * 16 + lr] = f2bf(z);
                    ls[nt] += z; lq[nt] += z * z;
                }
            }
        }
    }
#pragma unroll
    for (int nt = 0; nt < 4; ++nt) {
        ls[nt] += __shfl_down(ls[nt], 32); ls[nt] += __shfl_down(ls[nt], 16);
        lq[nt] += __shfl_down(lq[nt], 32); lq[nt] += __shfl_down(lq[nt], 16);
    }
    if (lane < 16) {
#pragma unroll
        for (int nt = 0; nt < 4; ++nt) {
            atomicAdd(&csumL[nbase + nt * 16 + lane], ls[nt]);
            atomicAdd(&csqL[nbase + nt * 16 + lane], lq[nt]);
        }
    }
    __syncthreads();
    if (tid < D) {
        atomicAdd(&colsum[tid], csumL[tid]);
        atomicAdd(&colsq[tid], csqL[tid]);
    }
}

// GEMM2: x = bf16( leaky(BN(H)@W2 + b2) + xres ); BN scale/shift computed per-block
// from colsum/colsq (kernel boundary after gemm1 guarantees visibility).
__global__ __launch_bounds__(256, 4)
void gemm2_mfma(const u16* __restrict__ HB, const u16* __restrict__ Wt,
                const float* __restrict__ bias,
                const float* __restrict__ colsum, const float* __restrict__ colsq,
                const float* __restrict__ gamma, const float* __restrict__ beta,
                const u16* __restrict__ xres, u16* __restrict__ xbout) {
    __shared__ u16 As[128 * 128];
    __shared__ float scL[D], shL[D];
    int tid = threadIdx.x;
    int row0 = blockIdx.x * 128;

    if (tid < D) {
        float m = colsum[tid] * (1.0f / N_NODES);
        float var = fmaxf(colsq[tid] * (1.0f / N_NODES) - m * m, 0.f);
        float sc = gamma[tid] * rsqrtf(var + EPS);
        scL[tid] = sc;
        shL[tid] = beta[tid] - m * sc;
    }
    __syncthreads();

#pragma unroll
    for (int i = 0; i < 8; ++i) {
        int q = i * 256 + tid;
        int m = q >> 4, kc = q & 15;
        uint4 av = make_uint4(0, 0, 0, 0);
        int gm = row0 + m;
        if (gm < N_NODES) {
            uint4 h = *(const uint4*)&HB[(size_t)gm * D + kc * 8];
            float4 s0 = *(const float4*)&scL[kc * 8];
            float4 s1 = *(const float4*)&scL[kc * 8 + 4];
            float4 t0 = *(const float4*)&shL[kc * 8];
            float4 t1 = *(const float4*)&shL[kc * 8 + 4];
            float f0 = bf2f(h.x & 0xffff) * s0.x + t0.x;
            float f1 = bf2f(h.x >> 16)    * s0.y + t0.y;
            float f2 = bf2f(h.y & 0xffff) * s0.z + t0.z;
            float f3 = bf2f(h.y >> 16)    * s0.w + t0.w;
            float f4 = bf2f(h.z & 0xffff) * s1.x + t1.x;
            float f5 = bf2f(h.z >> 16)    * s1.y + t1.y;
            float f6 = bf2f(h.w & 0xffff) * s1.z + t1.z;
            float f7 = bf2f(h.w >> 16)    * s1.w + t1.w;
            av.x = (u32)f2bf(f0) | ((u32)f2bf(f1) << 16);
            av.y = (u32)f2bf(f2) | ((u32)f2bf(f3) << 16);
            av.z = (u32)f2bf(f4) | ((u32)f2bf(f5) << 16);
            av.w = (u32)f2bf(f6) | ((u32)f2bf(f7) << 16);
        }
        *(uint4*)((char*)As + m * 256 + ((kc * 16) ^ ((m & 15) << 4))) = av;
    }
    __syncthreads();

    int lane = tid & 63;
    int wid = tid >> 6;
    int mbase = (wid >> 1) * 64, nbase = (wid & 1) * 64;
    int lr = lane & 15, kg = lane >> 4;
    f32x4 acc[4][4];
#pragma unroll
    for (int mt = 0; mt < 4; ++mt)
#pragma unroll
        for (int nt = 0; nt < 4; ++nt) acc[mt][nt] = (f32x4)0.0f;

    const char* Ap = (const char*)As;
#pragma unroll
    for (int ks = 0; ks < 4; ++ks) {
        int kb2 = ks * 64 + kg * 16;
        short8 af[4], bfr[4];
#pragma unroll
        for (int t = 0; t < 4; ++t) {
            int m = mbase + t * 16 + lr;
            af[t] = *(const short8*)(Ap + m * 256 + (kb2 ^ ((m & 15) << 4)));
            int n = nbase + t * 16 + lr;
            bfr[t] = *(const short8*)&Wt[n * D + ks * 32 + kg * 8];
        }
#pragma unroll
        for (int mt = 0; mt < 4; ++mt)
#pragma unroll
            for (int nt = 0; nt < 4; ++nt)
                acc[mt][nt] = __builtin_amdgcn_mfma_f32_16x16x32_bf16(af[mt], bfr[nt], acc[mt][nt], 0, 0, 0);
    }

    float bv[4];
#pragma unroll
    for (int nt = 0; nt < 4; ++nt) bv[nt] = bias[nbase + nt * 16 + lr];
#pragma unroll
    for (int mt = 0; mt < 4; ++mt) {
#pragma unroll
        for (int r = 0; r < 4; ++r) {
            int gm = row0 + mbase + mt * 16 + kg * 4 + r;
            if (gm < N_NODES) {
#pragma unroll
                for (int nt = 0; nt < 4; ++nt) {
                    int gn = nbase + nt * 16 + lr;
                    float z = acc[mt][nt][r] + bv[nt];
                    z = (z >= 0.f) ? z : 0.2f * z;
                    float o = z + bf2f((u32)xres[(size_t)gm * D + gn]);
                    xbout[(size_t)gm * D + gn] = f2bf(o);
                }
            }
        }
    }
}

// ---------------- pooling + final BN + fc ----------------

__global__ void bounds_kernel(const int* __restrict__ batch, int* __restrict__ gs, int* __restrict__ ge) {
    for (int i = blockIdx.x * blockDim.x + threadIdx.x; i < N_NODES; i += gridDim.x * blockDim.x) {
        int b = batch[i];
        atomicMin(&gs[b], i);
        atomicMax(&ge[b], i + 1);
    }
}

__global__ void pool_kernel(const u16* __restrict__ xb, const int* __restrict__ gs,
                            const int* __restrict__ ge, float* __restrict__ pooled) {
    int g = blockIdx.x, f = threadIdx.x;
    int s = gs[g], e = ge[g];
    float a0 = 0.f, a1 = 0.f, a2 = 0.f, a3 = 0.f;
    int i = s;
    for (; i + 4 <= e; i += 4) {
        a0 += bf2f((u32)xb[(size_t)i * D + f]);
        a1 += bf2f((u32)xb[(size_t)(i + 1) * D + f]);
        a2 += bf2f((u32)xb[(size_t)(i + 2) * D + f]);
        a3 += bf2f((u32)xb[(size_t)(i + 3) * D + f]);
    }
    for (; i < e; ++i) a0 += bf2f((u32)xb[(size_t)i * D + f]);
    pooled[g * D + f] = (a0 + a1) + (a2 + a3);
}

__global__ void pooled_bn(const float* __restrict__ pooled, const float* __restrict__ g,
                          const float* __restrict__ b, float* __restrict__ pscale,
                          float* __restrict__ pshift) {
    int c = threadIdx.x;
    float s = 0.f, q = 0.f;
    for (int gi = 0; gi < N_GRAPHS; ++gi) {
        float v = pooled[gi * D + c];
        s += v; q += v * v;
    }
    float m = s / N_GRAPHS;
    float var = q / N_GRAPHS - m * m;
    var = fmaxf(var, 0.f);
    float sc = g[c] * rsqrtf(var + EPS);
    pscale[c] = sc;
    pshift[c] = b[c] - m * sc;
}

__global__ void out_kernel(const float* __restrict__ pooled, const float* __restrict__ pscale,
                           const float* __restrict__ pshift, const float* __restrict__ fcW,
                           const float* __restrict__ fcb, float* __restrict__ out) {
    int idx = blockIdx.x * blockDim.x + threadIdx.x;
    if (idx >= N_GRAPHS * LATENT) return;
    int g = idx >> 6, j = idx & 63;
    float acc = fcb[j];
    for (int c = 0; c < D; ++c) {
        float pv = pooled[g * D + c] * pscale[c] + pshift[c];
        acc += pv * fcW[c * LATENT + j];
    }
    out[idx] = acc;
}

// ---------------- launch ----------------

extern "C" void kernel_launch(void* const* d_in, const int* in_sizes, int n_in,
                              void* d_out, int out_size, void* d_ws, size_t ws_size,
                              hipStream_t stream) {
    const float* x_in = (const float*)d_in[0];
    const int* edges  = (const int*)d_in[1];
    const int* batch  = (const int*)d_in[2];
    const float* W1   = (const float*)d_in[3];
    const float* b1   = (const float*)d_in[4];
    const float* g1   = (const float*)d_in[5];
    const float* bt1  = (const float*)d_in[6];
    const float* W2   = (const float*)d_in[7];
    const float* b2   = (const float*)d_in[8];
    const float* bng  = (const float*)d_in[9];
    const float* bnb  = (const float*)d_in[10];
    const float* fcW  = (const float*)d_in[11];
    const float* fcb  = (const float*)d_in[12];
    float* out = (float*)d_out;
    const int* srcp = edges;
    const int* dstp = edges + N_EDGES;

    char* p = (char*)d_ws;
    auto alloc = [&](size_t bytes) -> char* {
        char* r = p;
        p += (bytes + 511) & ~(size_t)511;
        return r;
    };
    u16*   XB      = (u16*)alloc((size_t)N_NODES * D * 2);     // bf16 x stream (residual+gather)
    u16*   AB      = (u16*)alloc((size_t)N_NODES * D * 2);     // agg out -> H (in place)
    int*   csr     = (int*)alloc((size_t)N_EDGES * 4);
    u32*   ebp     = (u32*)alloc((size_t)N_EDGES * 4);         // packed (src<<9)|dst_low
    int*   deg     = (int*)alloc((size_t)N_NODES * 4);
    int*   offsets = (int*)alloc((size_t)(N_NODES + 1) * 4);
    int*   bsum    = (int*)alloc((size_t)NB * 4);
    int*   boff    = (int*)alloc((size_t)NB * 4);
    int*   bhist   = (int*)alloc((size_t)NBUCK * 4);
    int*   bstart  = (int*)alloc((size_t)(NBUCK + 1) * 4);
    int*   gbcur   = (int*)alloc((size_t)NBUCK * 4);
    u16*   Wtb     = (u16*)alloc((size_t)6 * D * D * 2);       // bf16 transposed weights
    float* colsumA = (float*)alloc((size_t)6 * 256 * 4);       // [l]: sum@l*256, sq@l*256+128
    int*   gs      = (int*)alloc(N_GRAPHS * 4);
    int*   ge      = (int*)alloc(N_GRAPHS * 4);
    float* pooled  = (float*)alloc((size_t)N_GRAPHS * D * 4);
    float* pscale  = (float*)alloc(D * 4);
    float* pshift  = (float*)alloc(D * 4);

    init_misc<<<7 + CONVX_BLOCKS, 256, 0, stream>>>(W1, W2, Wtb, x_in, XB, colsumA,
                                                    bhist, gs, ge);

    const int EGRID = (N_EDGES + 4095) / 4096;   // 391
    bucket_hist<<<EGRID, 256, 0, stream>>>(dstp, bhist);
    bucket_scan<<<1, 256, 0, stream>>>(bhist, bstart, gbcur);
    bucket_scatter<<<EGRID, 256, 0, stream>>>(srcp, dstp, gbcur, ebp);
    hist_local<<<NBUCK, 256, 0, stream>>>(ebp, bstart, deg);
    scan_block_sum<<<NB, 256, 0, stream>>>(deg, bsum);
    scan_top<<<1, 512, 0, stream>>>(bsum, boff);
    scan_apply<<<NB, 256, 0, stream>>>(deg, boff, offsets);
    csr_fill_local<<<NBUCK, 256, 0, stream>>>(ebp, bstart, offsets, csr);

    const int GEMM_GRID = (N_NODES + 127) / 128;      // 782
    const int AGG_GRID = (N_NODES * 16 + 255) / 256;  // 6250
    for (int l = 0; l < 3; ++l) {
        agg_kernel<<<AGG_GRID, 256, 0, stream>>>(XB, csr, offsets, AB);
        gemm1_mfma<<<GEMM_GRID, 256, 0, stream>>>(AB, Wtb + (size_t)l * D * D, b1 + l * D,
                                                  colsumA + l * 256, colsumA + l * 256 + 128);
        gemm2_mfma<<<GEMM_GRID, 256, 0, stream>>>(AB, Wtb + (size_t)(3 + l) * D * D, b2 + l * D,
                                                  colsumA + l * 256, colsumA + l * 256 + 128,
                                                  g1 + l * D, bt1 + l * D, XB, XB);
    }

    bounds_kernel<<<256, 256, 0, stream>>>(batch, gs, ge);
    pool_kernel<<<N_GRAPHS, D, 0, stream>>>(XB, gs, ge, pooled);
    pooled_bn<<<1, D, 0, stream>>>(pooled, bng, bnb, pscale, pshift);
    out_kernel<<<(N_GRAPHS * LATENT + 255) / 256, 256, 0, stream>>>(pooled, pscale, pshift,
                                                                    fcW, fcb, out);
}

// Round 9
// 467.053 us; speedup vs baseline: 1.4709x; 1.1940x over previous
//
#include <hip/hip_runtime.h>

#define N_NODES 100000
#define N_EDGES 1600000
#define N_GRAPHS 1000
#define D 128
#define LATENT 64
#define EPS 1e-5f
#define NB ((N_NODES + 255) / 256)   // 391
#define NBUCK 196                    // buckets of 512 nodes: bucket = dst >> 9
#define BSH 9
#define CONVX_BLOCKS ((N_NODES * D / 4 + 255) / 256)   // 12500

typedef unsigned short u16;
typedef unsigned int u32;
typedef __attribute__((ext_vector_type(8))) short short8;   // 8 bf16 = 4 VGPR (MFMA A/B frag)
typedef __attribute__((ext_vector_type(4))) float f32x4;    // MFMA C/D frag

__device__ __forceinline__ float bf2f(u32 u) {
    union { u32 i; float f; } c; c.i = u << 16; return c.f;
}
__device__ __forceinline__ u16 f2bf(float f) {
    union { float f; u32 u; } c; c.f = f;
    u32 u = c.u;
    return (u16)((u + 0x7fffu + ((u >> 16) & 1u)) >> 16);   // RNE
}

// ---------------- fused init: weight convert + x convert + zero small bufs ----------------

__global__ void init_misc(const float* __restrict__ W1, const float* __restrict__ W2,
                          u16* __restrict__ Wt, const float* __restrict__ x,
                          u16* __restrict__ xb, float* __restrict__ colsumAll,
                          int* __restrict__ bhist,
                          int* __restrict__ gs, int* __restrict__ ge) {
    int b = blockIdx.x, t = threadIdx.x;
    if (b < 6) {
        const float* src = (b < 3) ? (W1 + (size_t)b * D * D) : (W2 + (size_t)(b - 3) * D * D);
        u16* dst = Wt + (size_t)b * D * D;
        for (int i = t; i < D * D; i += 256) {
            int k = i >> 7, n = i & 127;
            dst[n * D + k] = f2bf(src[i]);
        }
    } else if (b == 6) {
        for (int i = t; i < 6 * 256; i += 256) colsumAll[i] = 0.f;
        if (t < NBUCK) bhist[t] = 0;
        for (int i = t; i < N_GRAPHS; i += 256) { gs[i] = 0x7fffffff; ge[i] = 0; }
    } else {
        int idx = (b - 7) * 256 + t;
        if (idx < N_NODES * D / 4) {
            float4 v = *(const float4*)&x[(size_t)idx * 4];
            u32 lo = (u32)f2bf(v.x) | ((u32)f2bf(v.y) << 16);
            u32 hi = (u32)f2bf(v.z) | ((u32)f2bf(v.w) << 16);
            *(uint2*)&xb[(size_t)idx * 4] = make_uint2(lo, hi);
        }
    }
}

// ---------------- bucketed CSR build ----------------
// Edge staging packed: ebp = (src << 9) | (dst & 511); bucket = dst >> 9 implicit in range.

__global__ void bucket_hist(const int* __restrict__ dst, int* __restrict__ bhist) {
    __shared__ int cnt[256];
    int t = threadIdx.x;
    cnt[t] = 0;
    __syncthreads();
    int base = blockIdx.x * 4096 + t * 16;
#pragma unroll
    for (int i = 0; i < 16; ++i) {
        int e = base + i;
        if (e < N_EDGES) atomicAdd(&cnt[dst[e] >> BSH], 1);
    }
    __syncthreads();
    if (t < NBUCK && cnt[t] > 0) atomicAdd(&bhist[t], cnt[t]);
}

__global__ void bucket_scan(const int* __restrict__ bhist, int* __restrict__ bstart,
                            int* __restrict__ gbcur) {
    __shared__ int s[256];
    int t = threadIdx.x;
    int v = (t < NBUCK) ? bhist[t] : 0;
    s[t] = v;
    __syncthreads();
    for (int off = 1; off < 256; off <<= 1) {
        int a = (t >= off) ? s[t - off] : 0;
        __syncthreads();
        s[t] += a;
        __syncthreads();
    }
    if (t < NBUCK) { int ex = s[t] - v; bstart[t] = ex; gbcur[t] = ex; }
    if (t == NBUCK - 1) bstart[NBUCK] = s[t];
}

__global__ __launch_bounds__(256)
void bucket_scatter(const int* __restrict__ src, const int* __restrict__ dst,
                    int* __restrict__ gbcur, u32* __restrict__ ebp) {
    __shared__ int cnt[256], loff[256], basev[256], scn[256];
    __shared__ u32 pp[4096];
    __shared__ unsigned char pbkt[4096];
    int t = threadIdx.x;
    cnt[t] = 0;
    __syncthreads();
    int ebase = blockIdx.x * 4096;
    int b[16], r[16];
    u32 pk[16];
#pragma unroll
    for (int i = 0; i < 16; ++i) {
        int e = ebase + t * 16 + i;
        bool ok = e < N_EDGES;
        int d = ok ? dst[e] : 0;
        int sv = ok ? src[e] : 0;
        pk[i] = ((u32)sv << BSH) | (u32)(d & 511);
        b[i] = ok ? (d >> BSH) : -1;
    }
#pragma unroll
    for (int i = 0; i < 16; ++i)
        r[i] = (b[i] >= 0) ? atomicAdd(&cnt[b[i]], 1) : 0;
    __syncthreads();
    int c = cnt[t];
    scn[t] = c;
    __syncthreads();
    for (int off = 1; off < 256; off <<= 1) {
        int a = (t >= off) ? scn[t - off] : 0;
        __syncthreads();
        scn[t] += a;
        __syncthreads();
    }
    loff[t] = scn[t] - c;
    if (c > 0) basev[t] = atomicAdd(&gbcur[t], c);
    __syncthreads();
#pragma unroll
    for (int i = 0; i < 16; ++i) {
        if (b[i] >= 0) {
            int p = loff[b[i]] + r[i];
            pp[p] = pk[i];
            pbkt[p] = (unsigned char)b[i];
        }
    }
    __syncthreads();
    int total = min(4096, N_EDGES - ebase);
    for (int i = t; i < total; i += 256) {
        int bb = pbkt[i];
        int g = basev[bb] + (i - loff[bb]);
        ebp[g] = pp[i];
    }
}

__global__ void hist_local(const u32* __restrict__ ebp, const int* __restrict__ bstart,
                           int* __restrict__ deg) {
    __shared__ int h[512];
    int b = blockIdx.x, t = threadIdx.x;
    int nbase = b << BSH;
    h[t] = 0; h[t + 256] = 0;
    __syncthreads();
    int e0 = bstart[b], e1 = bstart[b + 1];
    for (int e = e0 + t; e < e1; e += 256)
        atomicAdd(&h[ebp[e] & 511], 1);
    __syncthreads();
    int nlen = min(512, N_NODES - nbase);
    if (t < nlen) deg[nbase + t] = h[t];
    if (t + 256 < nlen) deg[nbase + t + 256] = h[t + 256];
}

__global__ void scan_block_sum(const int* __restrict__ deg, int* __restrict__ bsum) {
    __shared__ int s[256];
    int t = threadIdx.x;
    int i = blockIdx.x * 256 + t;
    s[t] = (i < N_NODES) ? deg[i] : 0;
    __syncthreads();
    for (int off = 128; off > 0; off >>= 1) {
        if (t < off) s[t] += s[t + off];
        __syncthreads();
    }
    if (t == 0) bsum[blockIdx.x] = s[0];
}

__global__ void scan_top(const int* __restrict__ bsum, int* __restrict__ boff) {
    __shared__ int s[512];
    int t = threadIdx.x;
    int v = (t < NB) ? bsum[t] : 0;
    s[t] = v;
    __syncthreads();
    for (int off = 1; off < 512; off <<= 1) {
        int add = (t >= off) ? s[t - off] : 0;
        __syncthreads();
        s[t] += add;
        __syncthreads();
    }
    if (t < NB) boff[t] = s[t] - v;
}

__global__ void scan_apply(const int* __restrict__ deg, const int* __restrict__ boff,
                           int* __restrict__ offsets) {
    __shared__ int s[256];
    int t = threadIdx.x;
    int i = blockIdx.x * 256 + t;
    int v = (i < N_NODES) ? deg[i] : 0;
    s[t] = v;
    __syncthreads();
    for (int off = 1; off < 256; off <<= 1) {
        int add = (t >= off) ? s[t - off] : 0;
        __syncthreads();
        s[t] += add;
        __syncthreads();
    }
    int base = boff[blockIdx.x];
    if (i < N_NODES) offsets[i] = base + s[t] - v;
    if (i == N_NODES - 1) offsets[N_NODES] = base + s[t];
}

__global__ void csr_fill_local(const u32* __restrict__ ebp, const int* __restrict__ bstart,
                               const int* __restrict__ offsets, int* __restrict__ csr) {
    __shared__ int cur[512];
    int b = blockIdx.x, t = threadIdx.x;
    int nbase = b << BSH;
    int nlen = min(512, N_NODES - nbase);
    if (t < nlen) cur[t] = offsets[nbase + t];
    if (t + 256 < nlen) cur[t + 256] = offsets[nbase + t + 256];
    __syncthreads();
    int e0 = bstart[b], e1 = bstart[b + 1];
    for (int e = e0 + t; e < e1; e += 256) {
        u32 pk = ebp[e];
        int p = atomicAdd(&cur[pk & 511], 1);
        csr[p] = (int)(pk >> BSH);
    }
}

// ---------------- aggregation: ab = bf16( x + sum_{j->i} x_j ), x in bf16 ----------------
// 16 lanes/node, uint4 (8 bf16) per lane, 8-deep load batch -> 128B in flight/thread.

__device__ __forceinline__ void acc8(float* a, uint4 v) {
    a[0] += bf2f(v.x & 0xffff); a[1] += bf2f(v.x >> 16);
    a[2] += bf2f(v.y & 0xffff); a[3] += bf2f(v.y >> 16);
    a[4] += bf2f(v.z & 0xffff); a[5] += bf2f(v.z >> 16);
    a[6] += bf2f(v.w & 0xffff); a[7] += bf2f(v.w >> 16);
}

__global__ void agg_kernel(const u16* __restrict__ xb, const int* __restrict__ csr,
                           const int* __restrict__ offsets, u16* __restrict__ ab) {
    int t = blockIdx.x * blockDim.x + threadIdx.x;
    int node = t >> 4;
    if (node >= N_NODES) return;
    int lane = t & 15;
    const uint4* xp = (const uint4*)(xb + lane * 8);   // advance: 16 uint4 per row
    float a[8] = {0, 0, 0, 0, 0, 0, 0, 0};
    acc8(a, xp[(size_t)node * 16]);
    int s = offsets[node], e = offsets[node + 1];
    int p = s;
    for (; p + 8 <= e; p += 8) {
        int j0 = csr[p], j1 = csr[p + 1], j2 = csr[p + 2], j3 = csr[p + 3];
        int j4 = csr[p + 4], j5 = csr[p + 5], j6 = csr[p + 6], j7 = csr[p + 7];
        uint4 v0 = xp[(size_t)j0 * 16];
        uint4 v1 = xp[(size_t)j1 * 16];
        uint4 v2 = xp[(size_t)j2 * 16];
        uint4 v3 = xp[(size_t)j3 * 16];
        uint4 v4 = xp[(size_t)j4 * 16];
        uint4 v5 = xp[(size_t)j5 * 16];
        uint4 v6 = xp[(size_t)j6 * 16];
        uint4 v7 = xp[(size_t)j7 * 16];
        acc8(a, v0); acc8(a, v1); acc8(a, v2); acc8(a, v3);
        acc8(a, v4); acc8(a, v5); acc8(a, v6); acc8(a, v7);
    }
    for (; p + 4 <= e; p += 4) {
        int j0 = csr[p], j1 = csr[p + 1], j2 = csr[p + 2], j3 = csr[p + 3];
        uint4 v0 = xp[(size_t)j0 * 16];
        uint4 v1 = xp[(size_t)j1 * 16];
        uint4 v2 = xp[(size_t)j2 * 16];
        uint4 v3 = xp[(size_t)j3 * 16];
        acc8(a, v0); acc8(a, v1); acc8(a, v2); acc8(a, v3);
    }
    for (; p < e; ++p)
        acc8(a, xp[(size_t)csr[p] * 16]);
    uint4 o;
    o.x = (u32)f2bf(a[0]) | ((u32)f2bf(a[1]) << 16);
    o.y = (u32)f2bf(a[2]) | ((u32)f2bf(a[3]) << 16);
    o.z = (u32)f2bf(a[4]) | ((u32)f2bf(a[5]) << 16);
    o.w = (u32)f2bf(a[6]) | ((u32)f2bf(a[7]) << 16);
    *(uint4*)&ab[(size_t)node * D + lane * 8] = o;
}

// ---------------- MFMA GEMM common geometry ----------------
// 256 thr = 4 waves, BM=128, N=128, K=128. Wave (wid): rows (wid>>1)*64, cols (wid&1)*64.
// A staged in LDS (XOR-swizzle byte ^= ((row&15)<<4)); B frags read DIRECT from
// global Wt (32KB, L1/L2-resident) -> LDS ~33KB -> 4 blocks/CU.

// GEMM1: H = leaky(A@W1 + b1) bf16 IN PLACE over A; fused BN column stats.
__global__ __launch_bounds__(256, 4)
void gemm1_mfma(u16* __restrict__ AB, const u16* __restrict__ Wt,
                const float* __restrict__ bias,
                float* __restrict__ colsum, float* __restrict__ colsq) {
    __shared__ u16 As[128 * 128];
    __shared__ float csumL[D], csqL[D];
    int tid = threadIdx.x;
    int row0 = blockIdx.x * 128;

    if (tid < D) { csumL[tid] = 0.f; csqL[tid] = 0.f; }
#pragma unroll
    for (int i = 0; i < 8; ++i) {
        int q = i * 256 + tid;
        int m = q >> 4, kc = q & 15;
        uint4 av = make_uint4(0, 0, 0, 0);
        int gm = row0 + m;
        if (gm < N_NODES) av = *(const uint4*)&AB[(size_t)gm * D + kc * 8];
        *(uint4*)((char*)As + m * 256 + ((kc * 16) ^ ((m & 15) << 4))) = av;
    }
    __syncthreads();

    int lane = tid & 63;
    int wid = tid >> 6;
    int mbase = (wid >> 1) * 64, nbase = (wid & 1) * 64;
    int lr = lane & 15, kg = lane >> 4;
    f32x4 acc[4][4];
#pragma unroll
    for (int mt = 0; mt < 4; ++mt)
#pragma unroll
        for (int nt = 0; nt < 4; ++nt) acc[mt][nt] = (f32x4)0.0f;

    const char* Ap = (const char*)As;
#pragma unroll
    for (int ks = 0; ks < 4; ++ks) {
        int kb2 = ks * 64 + kg * 16;
        short8 af[4], bfr[4];
#pragma unroll
        for (int t = 0; t < 4; ++t) {
            int m = mbase + t * 16 + lr;
            af[t] = *(const short8*)(Ap + m * 256 + (kb2 ^ ((m & 15) << 4)));
            int n = nbase + t * 16 + lr;
            bfr[t] = *(const short8*)&Wt[n * D + ks * 32 + kg * 8];
        }
#pragma unroll
        for (int mt = 0; mt < 4; ++mt)
#pragma unroll
            for (int nt = 0; nt < 4; ++nt)
                acc[mt][nt] = __builtin_amdgcn_mfma_f32_16x16x32_bf16(af[mt], bfr[nt], acc[mt][nt], 0, 0, 0);
    }

    float bv[4], ls[4] = {0, 0, 0, 0}, lq[4] = {0, 0, 0, 0};
#pragma unroll
    for (int nt = 0; nt < 4; ++nt) bv[nt] = bias[nbase + nt * 16 + lr];
#pragma unroll
    for (int mt = 0; mt < 4; ++mt) {
#pragma unroll
        for (int r = 0; r < 4; ++r) {
            int gm = row0 + mbase + mt * 16 + kg * 4 + r;
            if (gm < N_NODES) {
#pragma unroll
                for (int nt = 0; nt < 4; ++nt) {
                    float z = acc[mt][nt][r] + bv[nt];
                    z = (z >= 0.f) ? z : 0.2f * z;
                    AB[(size_t)gm * D + nbase + nt * 16 + lr] = f2bf(z);
                    ls[nt] += z; lq[nt] += z * z;
                }
            }
        }
    }
#pragma unroll
    for (int nt = 0; nt < 4; ++nt) {
        ls[nt] += __shfl_down(ls[nt], 32); ls[nt] += __shfl_down(ls[nt], 16);
        lq[nt] += __shfl_down(lq[nt], 32); lq[nt] += __shfl_down(lq[nt], 16);
    }
    if (lane < 16) {
#pragma unroll
        for (int nt = 0; nt < 4; ++nt) {
            atomicAdd(&csumL[nbase + nt * 16 + lane], ls[nt]);
            atomicAdd(&csqL[nbase + nt * 16 + lane], lq[nt]);
        }
    }
    __syncthreads();
    if (tid < D) {
        atomicAdd(&colsum[tid], csumL[tid]);
        atomicAdd(&colsq[tid], csqL[tid]);
    }
}

// GEMM2: x = bf16( leaky(BN(H)@W2 + b2) + xres ); BN scale/shift computed per-block
// from colsum/colsq (kernel boundary after gemm1 guarantees visibility).
__global__ __launch_bounds__(256, 4)
void gemm2_mfma(const u16* __restrict__ HB, const u16* __restrict__ Wt,
                const float* __restrict__ bias,
                const float* __restrict__ colsum, const float* __restrict__ colsq,
                const float* __restrict__ gamma, const float* __restrict__ beta,
                const u16* __restrict__ xres, u16* __restrict__ xbout) {
    __shared__ u16 As[128 * 128];
    __shared__ float scL[D], shL[D];
    int tid = threadIdx.x;
    int row0 = blockIdx.x * 128;

    if (tid < D) {
        float m = colsum[tid] * (1.0f / N_NODES);
        float var = fmaxf(colsq[tid] * (1.0f / N_NODES) - m * m, 0.f);
        float sc = gamma[tid] * rsqrtf(var + EPS);
        scL[tid] = sc;
        shL[tid] = beta[tid] - m * sc;
    }
    __syncthreads();

#pragma unroll
    for (int i = 0; i < 8; ++i) {
        int q = i * 256 + tid;
        int m = q >> 4, kc = q & 15;
        uint4 av = make_uint4(0, 0, 0, 0);
        int gm = row0 + m;
        if (gm < N_NODES) {
            uint4 h = *(const uint4*)&HB[(size_t)gm * D + kc * 8];
            float4 s0 = *(const float4*)&scL[kc * 8];
            float4 s1 = *(const float4*)&scL[kc * 8 + 4];
            float4 t0 = *(const float4*)&shL[kc * 8];
            float4 t1 = *(const float4*)&shL[kc * 8 + 4];
            float f0 = bf2f(h.x & 0xffff) * s0.x + t0.x;
            float f1 = bf2f(h.x >> 16)    * s0.y + t0.y;
            float f2 = bf2f(h.y & 0xffff) * s0.z + t0.z;
            float f3 = bf2f(h.y >> 16)    * s0.w + t0.w;
            float f4 = bf2f(h.z & 0xffff) * s1.x + t1.x;
            float f5 = bf2f(h.z >> 16)    * s1.y + t1.y;
            float f6 = bf2f(h.w & 0xffff) * s1.z + t1.z;
            float f7 = bf2f(h.w >> 16)    * s1.w + t1.w;
            av.x = (u32)f2bf(f0) | ((u32)f2bf(f1) << 16);
            av.y = (u32)f2bf(f2) | ((u32)f2bf(f3) << 16);
            av.z = (u32)f2bf(f4) | ((u32)f2bf(f5) << 16);
            av.w = (u32)f2bf(f6) | ((u32)f2bf(f7) << 16);
        }
        *(uint4*)((char*)As + m * 256 + ((kc * 16) ^ ((m & 15) << 4))) = av;
    }
    __syncthreads();

    int lane = tid & 63;
    int wid = tid >> 6;
    int mbase = (wid >> 1) * 64, nbase = (wid & 1) * 64;
    int lr = lane & 15, kg = lane >> 4;
    f32x4 acc[4][4];
#pragma unroll
    for (int mt = 0; mt < 4; ++mt)
#pragma unroll
        for (int nt = 0; nt < 4; ++nt) acc[mt][nt] = (f32x4)0.0f;

    const char* Ap = (const char*)As;
#pragma unroll
    for (int ks = 0; ks < 4; ++ks) {
        int kb2 = ks * 64 + kg * 16;
        short8 af[4], bfr[4];
#pragma unroll
        for (int t = 0; t < 4; ++t) {
            int m = mbase + t * 16 + lr;
            af[t] = *(const short8*)(Ap + m * 256 + (kb2 ^ ((m & 15) << 4)));
            int n = nbase + t * 16 + lr;
            bfr[t] = *(const short8*)&Wt[n * D + ks * 32 + kg * 8];
        }
#pragma unroll
        for (int mt = 0; mt < 4; ++mt)
#pragma unroll
            for (int nt = 0; nt < 4; ++nt)
                acc[mt][nt] = __builtin_amdgcn_mfma_f32_16x16x32_bf16(af[mt], bfr[nt], acc[mt][nt], 0, 0, 0);
    }

    float bv[4];
#pragma unroll
    for (int nt = 0; nt < 4; ++nt) bv[nt] = bias[nbase + nt * 16 + lr];
#pragma unroll
    for (int mt = 0; mt < 4; ++mt) {
#pragma unroll
        for (int r = 0; r < 4; ++r) {
            int gm = row0 + mbase + mt * 16 + kg * 4 + r;
            if (gm < N_NODES) {
#pragma unroll
                for (int nt = 0; nt < 4; ++nt) {
                    int gn = nbase + nt * 16 + lr;
                    float z = acc[mt][nt][r] + bv[nt];
                    z = (z >= 0.f) ? z : 0.2f * z;
                    float o = z + bf2f((u32)xres[(size_t)gm * D + gn]);
                    xbout[(size_t)gm * D + gn] = f2bf(o);
                }
            }
        }
    }
}

// ---------------- pooling + final BN + fc ----------------

// batch is SORTED: detect boundaries with adjacent compares; no atomics.
__global__ void bounds_kernel(const int* __restrict__ batch, int* __restrict__ gs, int* __restrict__ ge) {
    int i = blockIdx.x * blockDim.x + threadIdx.x;
    if (i >= N_NODES) return;
    int b = batch[i];
    if (i == 0) {
        gs[b] = 0;
    } else {
        int bp = batch[i - 1];
        if (bp != b) { gs[b] = i; ge[bp] = i; }
    }
    if (i == N_NODES - 1) ge[b] = N_NODES;
}

__global__ void pool_kernel(const u16* __restrict__ xb, const int* __restrict__ gs,
                            const int* __restrict__ ge, float* __restrict__ pooled) {
    int g = blockIdx.x, f = threadIdx.x;
    int s = gs[g], e = ge[g];
    float a0 = 0.f, a1 = 0.f, a2 = 0.f, a3 = 0.f;
    int i = s;
    for (; i + 4 <= e; i += 4) {
        a0 += bf2f((u32)xb[(size_t)i * D + f]);
        a1 += bf2f((u32)xb[(size_t)(i + 1) * D + f]);
        a2 += bf2f((u32)xb[(size_t)(i + 2) * D + f]);
        a3 += bf2f((u32)xb[(size_t)(i + 3) * D + f]);
    }
    for (; i < e; ++i) a0 += bf2f((u32)xb[(size_t)i * D + f]);
    pooled[g * D + f] = (a0 + a1) + (a2 + a3);
}

// 128 blocks (one per feature) x 256 threads; shfl + LDS reduce.
__global__ void pooled_bn(const float* __restrict__ pooled, const float* __restrict__ g,
                          const float* __restrict__ b, float* __restrict__ pscale,
                          float* __restrict__ pshift) {
    int c = blockIdx.x;
    int t = threadIdx.x;
    float s = 0.f, q = 0.f;
    for (int gi = t; gi < N_GRAPHS; gi += 256) {
        float v = pooled[gi * D + c];
        s += v; q += v * v;
    }
#pragma unroll
    for (int off = 32; off > 0; off >>= 1) {
        s += __shfl_down(s, off);
        q += __shfl_down(q, off);
    }
    __shared__ float ss[4], qq[4];
    int lane = t & 63, w = t >> 6;
    if (lane == 0) { ss[w] = s; qq[w] = q; }
    __syncthreads();
    if (t == 0) {
        float S = (ss[0] + ss[1]) + (ss[2] + ss[3]);
        float Q = (qq[0] + qq[1]) + (qq[2] + qq[3]);
        float m = S / N_GRAPHS;
        float var = fmaxf(Q / N_GRAPHS - m * m, 0.f);
        float sc = g[c] * rsqrtf(var + EPS);
        pscale[c] = sc;
        pshift[c] = b[c] - m * sc;
    }
}

__global__ void out_kernel(const float* __restrict__ pooled, const float* __restrict__ pscale,
                           const float* __restrict__ pshift, const float* __restrict__ fcW,
                           const float* __restrict__ fcb, float* __restrict__ out) {
    int idx = blockIdx.x * blockDim.x + threadIdx.x;
    if (idx >= N_GRAPHS * LATENT) return;
    int g = idx >> 6, j = idx & 63;
    float acc = fcb[j];
    for (int c = 0; c < D; ++c) {
        float pv = pooled[g * D + c] * pscale[c] + pshift[c];
        acc += pv * fcW[c * LATENT + j];
    }
    out[idx] = acc;
}

// ---------------- launch ----------------

extern "C" void kernel_launch(void* const* d_in, const int* in_sizes, int n_in,
                              void* d_out, int out_size, void* d_ws, size_t ws_size,
                              hipStream_t stream) {
    const float* x_in = (const float*)d_in[0];
    const int* edges  = (const int*)d_in[1];
    const int* batch  = (const int*)d_in[2];
    const float* W1   = (const float*)d_in[3];
    const float* b1   = (const float*)d_in[4];
    const float* g1   = (const float*)d_in[5];
    const float* bt1  = (const float*)d_in[6];
    const float* W2   = (const float*)d_in[7];
    const float* b2   = (const float*)d_in[8];
    const float* bng  = (const float*)d_in[9];
    const float* bnb  = (const float*)d_in[10];
    const float* fcW  = (const float*)d_in[11];
    const float* fcb  = (const float*)d_in[12];
    float* out = (float*)d_out;
    const int* srcp = edges;
    const int* dstp = edges + N_EDGES;

    char* p = (char*)d_ws;
    auto alloc = [&](size_t bytes) -> char* {
        char* r = p;
        p += (bytes + 511) & ~(size_t)511;
        return r;
    };
    u16*   XB      = (u16*)alloc((size_t)N_NODES * D * 2);     // bf16 x stream (residual+gather)
    u16*   AB      = (u16*)alloc((size_t)N_NODES * D * 2);     // agg out -> H (in place)
    int*   csr     = (int*)alloc((size_t)N_EDGES * 4);
    u32*   ebp     = (u32*)alloc((size_t)N_EDGES * 4);         // packed (src<<9)|dst_low
    int*   deg     = (int*)alloc((size_t)N_NODES * 4);
    int*   offsets = (int*)alloc((size_t)(N_NODES + 1) * 4);
    int*   bsum    = (int*)alloc((size_t)NB * 4);
    int*   boff    = (int*)alloc((size_t)NB * 4);
    int*   bhist   = (int*)alloc((size_t)NBUCK * 4);
    int*   bstart  = (int*)alloc((size_t)(NBUCK + 1) * 4);
    int*   gbcur   = (int*)alloc((size_t)NBUCK * 4);
    u16*   Wtb     = (u16*)alloc((size_t)6 * D * D * 2);       // bf16 transposed weights
    float* colsumA = (float*)alloc((size_t)6 * 256 * 4);       // [l]: sum@l*256, sq@l*256+128
    int*   gs      = (int*)alloc(N_GRAPHS * 4);
    int*   ge      = (int*)alloc(N_GRAPHS * 4);
    float* pooled  = (float*)alloc((size_t)N_GRAPHS * D * 4);
    float* pscale  = (float*)alloc(D * 4);
    float* pshift  = (float*)alloc(D * 4);

    init_misc<<<7 + CONVX_BLOCKS, 256, 0, stream>>>(W1, W2, Wtb, x_in, XB, colsumA,
                                                    bhist, gs, ge);

    const int EGRID = (N_EDGES + 4095) / 4096;   // 391
    bucket_hist<<<EGRID, 256, 0, stream>>>(dstp, bhist);
    bucket_scan<<<1, 256, 0, stream>>>(bhist, bstart, gbcur);
    bucket_scatter<<<EGRID, 256, 0, stream>>>(srcp, dstp, gbcur, ebp);
    hist_local<<<NBUCK, 256, 0, stream>>>(ebp, bstart, deg);
    scan_block_sum<<<NB, 256, 0, stream>>>(deg, bsum);
    scan_top<<<1, 512, 0, stream>>>(bsum, boff);
    scan_apply<<<NB, 256, 0, stream>>>(deg, boff, offsets);
    csr_fill_local<<<NBUCK, 256, 0, stream>>>(ebp, bstart, offsets, csr);

    const int GEMM_GRID = (N_NODES + 127) / 128;      // 782
    const int AGG_GRID = (N_NODES * 16 + 255) / 256;  // 6250
    for (int l = 0; l < 3; ++l) {
        agg_kernel<<<AGG_GRID, 256, 0, stream>>>(XB, csr, offsets, AB);
        gemm1_mfma<<<GEMM_GRID, 256, 0, stream>>>(AB, Wtb + (size_t)l * D * D, b1 + l * D,
                                                  colsumA + l * 256, colsumA + l * 256 + 128);
        gemm2_mfma<<<GEMM_GRID, 256, 0, stream>>>(AB, Wtb + (size_t)(3 + l) * D * D, b2 + l * D,
                                                  colsumA + l * 256, colsumA + l * 256 + 128,
                                                  g1 + l * D, bt1 + l * D, XB, XB);
    }

    bounds_kernel<<<NB, 256, 0, stream>>>(batch, gs, ge);
    pool_kernel<<<N_GRAPHS, D, 0, stream>>>(XB, gs, ge, pooled);
    pooled_bn<<<D, 256, 0, stream>>>(pooled, bng, bnb, pscale, pshift);
    out_kernel<<<(N_GRAPHS * LATENT + 255) / 256, 256, 0, stream>>>(pooled, pscale, pshift,
                                                                    fcW, fcb, out);
}

// Round 10
// 434.356 us; speedup vs baseline: 1.5816x; 1.0753x over previous
//
#include <hip/hip_runtime.h>

#define N_NODES 100000
#define N_EDGES 1600000
#define N_GRAPHS 1000
#define D 128
#define LATENT 64
#define EPS 1e-5f
#define NB ((N_NODES + 255) / 256)   // 391
#define NBUCK 196                    // buckets of 512 nodes: bucket = dst >> 9
#define BSH 9
#define CONVX_BLOCKS ((N_NODES * D / 4 + 255) / 256)   // 12500

typedef unsigned short u16;
typedef unsigned int u32;
typedef __attribute__((ext_vector_type(8))) short short8;   // 8 bf16 = 4 VGPR (MFMA A/B frag)
typedef __attribute__((ext_vector_type(4))) float f32x4;    // MFMA C/D frag

__device__ __forceinline__ float bf2f(u32 u) {
    union { u32 i; float f; } c; c.i = u << 16; return c.f;
}
__device__ __forceinline__ u16 f2bf(float f) {
    union { float f; u32 u; } c; c.f = f;
    u32 u = c.u;
    return (u16)((u + 0x7fffu + ((u >> 16) & 1u)) >> 16);   // RNE
}

// ---------------- fused init: weight convert + x convert + zero small bufs ----------------

__global__ void init_misc(const float* __restrict__ W1, const float* __restrict__ W2,
                          u16* __restrict__ Wt, const float* __restrict__ x,
                          u16* __restrict__ xb, float* __restrict__ colsumAll,
                          int* __restrict__ bhist,
                          int* __restrict__ gs, int* __restrict__ ge) {
    int b = blockIdx.x, t = threadIdx.x;
    if (b < 6) {
        const float* src = (b < 3) ? (W1 + (size_t)b * D * D) : (W2 + (size_t)(b - 3) * D * D);
        u16* dst = Wt + (size_t)b * D * D;
        for (int i = t; i < D * D; i += 256) {
            int k = i >> 7, n = i & 127;
            dst[n * D + k] = f2bf(src[i]);
        }
    } else if (b == 6) {
        for (int i = t; i < 6 * 256; i += 256) colsumAll[i] = 0.f;
        if (t < NBUCK) bhist[t] = 0;
        for (int i = t; i < N_GRAPHS; i += 256) { gs[i] = 0x7fffffff; ge[i] = 0; }
    } else {
        int idx = (b - 7) * 256 + t;
        if (idx < N_NODES * D / 4) {
            float4 v = *(const float4*)&x[(size_t)idx * 4];
            u32 lo = (u32)f2bf(v.x) | ((u32)f2bf(v.y) << 16);
            u32 hi = (u32)f2bf(v.z) | ((u32)f2bf(v.w) << 16);
            *(uint2*)&xb[(size_t)idx * 4] = make_uint2(lo, hi);
        }
    }
}

// ---------------- bucketed CSR build ----------------
// Edge staging packed: ebp = (src << 9) | (dst & 511); bucket = dst >> 9 implicit in range.

__global__ void bucket_hist(const int* __restrict__ dst, int* __restrict__ bhist) {
    __shared__ int cnt[256];
    int t = threadIdx.x;
    cnt[t] = 0;
    __syncthreads();
    int base = blockIdx.x * 4096 + t * 16;
#pragma unroll
    for (int i = 0; i < 16; ++i) {
        int e = base + i;
        if (e < N_EDGES) atomicAdd(&cnt[dst[e] >> BSH], 1);
    }
    __syncthreads();
    if (t < NBUCK && cnt[t] > 0) atomicAdd(&bhist[t], cnt[t]);
}

__global__ void bucket_scan(const int* __restrict__ bhist, int* __restrict__ bstart,
                            int* __restrict__ gbcur) {
    __shared__ int s[256];
    int t = threadIdx.x;
    int v = (t < NBUCK) ? bhist[t] : 0;
    s[t] = v;
    __syncthreads();
    for (int off = 1; off < 256; off <<= 1) {
        int a = (t >= off) ? s[t - off] : 0;
        __syncthreads();
        s[t] += a;
        __syncthreads();
    }
    if (t < NBUCK) { int ex = s[t] - v; bstart[t] = ex; gbcur[t] = ex; }
    if (t == NBUCK - 1) bstart[NBUCK] = s[t];
}

__global__ __launch_bounds__(256)
void bucket_scatter(const int* __restrict__ src, const int* __restrict__ dst,
                    int* __restrict__ gbcur, u32* __restrict__ ebp) {
    __shared__ int cnt[256], loff[256], basev[256], scn[256];
    __shared__ u32 pp[4096];
    __shared__ unsigned char pbkt[4096];
    int t = threadIdx.x;
    cnt[t] = 0;
    __syncthreads();
    int ebase = blockIdx.x * 4096;
    int b[16], r[16];
    u32 pk[16];
#pragma unroll
    for (int i = 0; i < 16; ++i) {
        int e = ebase + t * 16 + i;
        bool ok = e < N_EDGES;
        int d = ok ? dst[e] : 0;
        int sv = ok ? src[e] : 0;
        pk[i] = ((u32)sv << BSH) | (u32)(d & 511);
        b[i] = ok ? (d >> BSH) : -1;
    }
#pragma unroll
    for (int i = 0; i < 16; ++i)
        r[i] = (b[i] >= 0) ? atomicAdd(&cnt[b[i]], 1) : 0;
    __syncthreads();
    int c = cnt[t];
    scn[t] = c;
    __syncthreads();
    for (int off = 1; off < 256; off <<= 1) {
        int a = (t >= off) ? scn[t - off] : 0;
        __syncthreads();
        scn[t] += a;
        __syncthreads();
    }
    loff[t] = scn[t] - c;
    if (c > 0) basev[t] = atomicAdd(&gbcur[t], c);
    __syncthreads();
#pragma unroll
    for (int i = 0; i < 16; ++i) {
        if (b[i] >= 0) {
            int p = loff[b[i]] + r[i];
            pp[p] = pk[i];
            pbkt[p] = (unsigned char)b[i];
        }
    }
    __syncthreads();
    int total = min(4096, N_EDGES - ebase);
    for (int i = t; i < total; i += 256) {
        int bb = pbkt[i];
        int g = basev[bb] + (i - loff[bb]);
        ebp[g] = pp[i];
    }
}

__global__ void hist_local(const u32* __restrict__ ebp, const int* __restrict__ bstart,
                           int* __restrict__ deg) {
    __shared__ int h[512];
    int b = blockIdx.x, t = threadIdx.x;
    int nbase = b << BSH;
    h[t] = 0; h[t + 256] = 0;
    __syncthreads();
    int e0 = bstart[b], e1 = bstart[b + 1];
    for (int e = e0 + t; e < e1; e += 256)
        atomicAdd(&h[ebp[e] & 511], 1);
    __syncthreads();
    int nlen = min(512, N_NODES - nbase);
    if (t < nlen) deg[nbase + t] = h[t];
    if (t + 256 < nlen) deg[nbase + t + 256] = h[t + 256];
}

__global__ void scan_block_sum(const int* __restrict__ deg, int* __restrict__ bsum) {
    __shared__ int s[256];
    int t = threadIdx.x;
    int i = blockIdx.x * 256 + t;
    s[t] = (i < N_NODES) ? deg[i] : 0;
    __syncthreads();
    for (int off = 128; off > 0; off >>= 1) {
        if (t < off) s[t] += s[t + off];
        __syncthreads();
    }
    if (t == 0) bsum[blockIdx.x] = s[0];
}

__global__ void scan_top(const int* __restrict__ bsum, int* __restrict__ boff) {
    __shared__ int s[512];
    int t = threadIdx.x;
    int v = (t < NB) ? bsum[t] : 0;
    s[t] = v;
    __syncthreads();
    for (int off = 1; off < 512; off <<= 1) {
        int add = (t >= off) ? s[t - off] : 0;
        __syncthreads();
        s[t] += add;
        __syncthreads();
    }
    if (t < NB) boff[t] = s[t] - v;
}

__global__ void scan_apply(const int* __restrict__ deg, const int* __restrict__ boff,
                           int* __restrict__ offsets) {
    __shared__ int s[256];
    int t = threadIdx.x;
    int i = blockIdx.x * 256 + t;
    int v = (i < N_NODES) ? deg[i] : 0;
    s[t] = v;
    __syncthreads();
    for (int off = 1; off < 256; off <<= 1) {
        int add = (t >= off) ? s[t - off] : 0;
        __syncthreads();
        s[t] += add;
        __syncthreads();
    }
    int base = boff[blockIdx.x];
    if (i < N_NODES) offsets[i] = base + s[t] - v;
    if (i == N_NODES - 1) offsets[N_NODES] = base + s[t];
}

__global__ void csr_fill_local(const u32* __restrict__ ebp, const int* __restrict__ bstart,
                               const int* __restrict__ offsets, int* __restrict__ csr) {
    __shared__ int cur[512];
    int b = blockIdx.x, t = threadIdx.x;
    int nbase = b << BSH;
    int nlen = min(512, N_NODES - nbase);
    if (t < nlen) cur[t] = offsets[nbase + t];
    if (t + 256 < nlen) cur[t + 256] = offsets[nbase + t + 256];
    __syncthreads();
    int e0 = bstart[b], e1 = bstart[b + 1];
    for (int e = e0 + t; e < e1; e += 256) {
        u32 pk = ebp[e];
        int p = atomicAdd(&cur[pk & 511], 1);
        csr[p] = (int)(pk >> BSH);
    }
}

// ---------------- fused agg + GEMM1 ----------------
// Block = 128 rows. Phase 1 (gather): 8 passes x 16 nodes, 16 lanes/node, 8-deep
// MLP edge loop; agg result packed bf16 straight into the swizzled LDS A-tile.
// Phase 2 (MFMA): H = leaky(A@W1 + b1) written bf16 to HB; fused BN col stats.
// B frags read direct from global Wt (32KB, L2-resident). LDS ~33KB -> 4 blocks/CU.

__device__ __forceinline__ void acc8(float* a, uint4 v) {
    a[0] += bf2f(v.x & 0xffff); a[1] += bf2f(v.x >> 16);
    a[2] += bf2f(v.y & 0xffff); a[3] += bf2f(v.y >> 16);
    a[4] += bf2f(v.z & 0xffff); a[5] += bf2f(v.z >> 16);
    a[6] += bf2f(v.w & 0xffff); a[7] += bf2f(v.w >> 16);
}

__global__ __launch_bounds__(256, 4)
void agg_gemm1_mfma(const u16* __restrict__ xb, const int* __restrict__ csr,
                    const int* __restrict__ offsets,
                    const u16* __restrict__ Wt, const float* __restrict__ bias,
                    u16* __restrict__ HB,
                    float* __restrict__ colsum, float* __restrict__ colsq) {
    __shared__ u16 As[128 * 128];
    __shared__ float csumL[D], csqL[D];
    int tid = threadIdx.x;
    int row0 = blockIdx.x * 128;

    if (tid < D) { csumL[tid] = 0.f; csqL[tid] = 0.f; }

    // ---- gather phase ----
    int lane16 = tid & 15;
    const uint4* xp = (const uint4*)xb + lane16;   // 16 uint4 per row
#pragma unroll 1
    for (int pass = 0; pass < 8; ++pass) {
        int m = pass * 16 + (tid >> 4);
        int node = row0 + m;
        float a[8] = {0, 0, 0, 0, 0, 0, 0, 0};
        if (node < N_NODES) {
            acc8(a, xp[(size_t)node * 16]);
            int s = offsets[node], e = offsets[node + 1];
            int p = s;
            for (; p + 8 <= e; p += 8) {
                int j0 = csr[p], j1 = csr[p + 1], j2 = csr[p + 2], j3 = csr[p + 3];
                int j4 = csr[p + 4], j5 = csr[p + 5], j6 = csr[p + 6], j7 = csr[p + 7];
                uint4 v0 = xp[(size_t)j0 * 16];
                uint4 v1 = xp[(size_t)j1 * 16];
                uint4 v2 = xp[(size_t)j2 * 16];
                uint4 v3 = xp[(size_t)j3 * 16];
                uint4 v4 = xp[(size_t)j4 * 16];
                uint4 v5 = xp[(size_t)j5 * 16];
                uint4 v6 = xp[(size_t)j6 * 16];
                uint4 v7 = xp[(size_t)j7 * 16];
                acc8(a, v0); acc8(a, v1); acc8(a, v2); acc8(a, v3);
                acc8(a, v4); acc8(a, v5); acc8(a, v6); acc8(a, v7);
            }
            for (; p + 4 <= e; p += 4) {
                int j0 = csr[p], j1 = csr[p + 1], j2 = csr[p + 2], j3 = csr[p + 3];
                uint4 v0 = xp[(size_t)j0 * 16];
                uint4 v1 = xp[(size_t)j1 * 16];
                uint4 v2 = xp[(size_t)j2 * 16];
                uint4 v3 = xp[(size_t)j3 * 16];
                acc8(a, v0); acc8(a, v1); acc8(a, v2); acc8(a, v3);
            }
            for (; p < e; ++p)
                acc8(a, xp[(size_t)csr[p] * 16]);
        }
        uint4 o;
        o.x = (u32)f2bf(a[0]) | ((u32)f2bf(a[1]) << 16);
        o.y = (u32)f2bf(a[2]) | ((u32)f2bf(a[3]) << 16);
        o.z = (u32)f2bf(a[4]) | ((u32)f2bf(a[5]) << 16);
        o.w = (u32)f2bf(a[6]) | ((u32)f2bf(a[7]) << 16);
        *(uint4*)((char*)As + m * 256 + ((lane16 * 16) ^ ((m & 15) << 4))) = o;
    }
    __syncthreads();

    // ---- MFMA phase ----
    int lane = tid & 63;
    int wid = tid >> 6;
    int mbase = (wid >> 1) * 64, nbase = (wid & 1) * 64;
    int lr = lane & 15, kg = lane >> 4;
    f32x4 acc[4][4];
#pragma unroll
    for (int mt = 0; mt < 4; ++mt)
#pragma unroll
        for (int nt = 0; nt < 4; ++nt) acc[mt][nt] = (f32x4)0.0f;

    const char* Ap = (const char*)As;
#pragma unroll
    for (int ks = 0; ks < 4; ++ks) {
        int kb2 = ks * 64 + kg * 16;
        short8 af[4], bfr[4];
#pragma unroll
        for (int t = 0; t < 4; ++t) {
            int m = mbase + t * 16 + lr;
            af[t] = *(const short8*)(Ap + m * 256 + (kb2 ^ ((m & 15) << 4)));
            int n = nbase + t * 16 + lr;
            bfr[t] = *(const short8*)&Wt[n * D + ks * 32 + kg * 8];
        }
#pragma unroll
        for (int mt = 0; mt < 4; ++mt)
#pragma unroll
            for (int nt = 0; nt < 4; ++nt)
                acc[mt][nt] = __builtin_amdgcn_mfma_f32_16x16x32_bf16(af[mt], bfr[nt], acc[mt][nt], 0, 0, 0);
    }

    float bv[4], ls[4] = {0, 0, 0, 0}, lq[4] = {0, 0, 0, 0};
#pragma unroll
    for (int nt = 0; nt < 4; ++nt) bv[nt] = bias[nbase + nt * 16 + lr];
#pragma unroll
    for (int mt = 0; mt < 4; ++mt) {
#pragma unroll
        for (int r = 0; r < 4; ++r) {
            int gm = row0 + mbase + mt * 16 + kg * 4 + r;
            if (gm < N_NODES) {
#pragma unroll
                for (int nt = 0; nt < 4; ++nt) {
                    float z = acc[mt][nt][r] + bv[nt];
                    z = (z >= 0.f) ? z : 0.2f * z;
                    HB[(size_t)gm * D + nbase + nt * 16 + lr] = f2bf(z);
                    ls[nt] += z; lq[nt] += z * z;
                }
            }
        }
    }
#pragma unroll
    for (int nt = 0; nt < 4; ++nt) {
        ls[nt] += __shfl_down(ls[nt], 32); ls[nt] += __shfl_down(ls[nt], 16);
        lq[nt] += __shfl_down(lq[nt], 32); lq[nt] += __shfl_down(lq[nt], 16);
    }
    if (lane < 16) {
#pragma unroll
        for (int nt = 0; nt < 4; ++nt) {
            atomicAdd(&csumL[nbase + nt * 16 + lane], ls[nt]);
            atomicAdd(&csqL[nbase + nt * 16 + lane], lq[nt]);
        }
    }
    __syncthreads();
    if (tid < D) {
        atomicAdd(&colsum[tid], csumL[tid]);
        atomicAdd(&colsq[tid], csqL[tid]);
    }
}

// GEMM2: x = bf16( leaky(BN(H)@W2 + b2) + xres ); BN scale/shift computed per-block
// from colsum/colsq (kernel boundary after agg_gemm1 guarantees visibility).
__global__ __launch_bounds__(256, 4)
void gemm2_mfma(const u16* __restrict__ HB, const u16* __restrict__ Wt,
                const float* __restrict__ bias,
                const float* __restrict__ colsum, const float* __restrict__ colsq,
                const float* __restrict__ gamma, const float* __restrict__ beta,
                const u16* __restrict__ xres, u16* __restrict__ xbout) {
    __shared__ u16 As[128 * 128];
    __shared__ float scL[D], shL[D];
    int tid = threadIdx.x;
    int row0 = blockIdx.x * 128;

    if (tid < D) {
        float m = colsum[tid] * (1.0f / N_NODES);
        float var = fmaxf(colsq[tid] * (1.0f / N_NODES) - m * m, 0.f);
        float sc = gamma[tid] * rsqrtf(var + EPS);
        scL[tid] = sc;
        shL[tid] = beta[tid] - m * sc;
    }
    __syncthreads();

#pragma unroll
    for (int i = 0; i < 8; ++i) {
        int q = i * 256 + tid;
        int m = q >> 4, kc = q & 15;
        uint4 av = make_uint4(0, 0, 0, 0);
        int gm = row0 + m;
        if (gm < N_NODES) {
            uint4 h = *(const uint4*)&HB[(size_t)gm * D + kc * 8];
            float4 s0 = *(const float4*)&scL[kc * 8];
            float4 s1 = *(const float4*)&scL[kc * 8 + 4];
            float4 t0 = *(const float4*)&shL[kc * 8];
            float4 t1 = *(const float4*)&shL[kc * 8 + 4];
            float f0 = bf2f(h.x & 0xffff) * s0.x + t0.x;
            float f1 = bf2f(h.x >> 16)    * s0.y + t0.y;
            float f2 = bf2f(h.y & 0xffff) * s0.z + t0.z;
            float f3 = bf2f(h.y >> 16)    * s0.w + t0.w;
            float f4 = bf2f(h.z & 0xffff) * s1.x + t1.x;
            float f5 = bf2f(h.z >> 16)    * s1.y + t1.y;
            float f6 = bf2f(h.w & 0xffff) * s1.z + t1.z;
            float f7 = bf2f(h.w >> 16)    * s1.w + t1.w;
            av.x = (u32)f2bf(f0) | ((u32)f2bf(f1) << 16);
            av.y = (u32)f2bf(f2) | ((u32)f2bf(f3) << 16);
            av.z = (u32)f2bf(f4) | ((u32)f2bf(f5) << 16);
            av.w = (u32)f2bf(f6) | ((u32)f2bf(f7) << 16);
        }
        *(uint4*)((char*)As + m * 256 + ((kc * 16) ^ ((m & 15) << 4))) = av;
    }
    __syncthreads();

    int lane = tid & 63;
    int wid = tid >> 6;
    int mbase = (wid >> 1) * 64, nbase = (wid & 1) * 64;
    int lr = lane & 15, kg = lane >> 4;
    f32x4 acc[4][4];
#pragma unroll
    for (int mt = 0; mt < 4; ++mt)
#pragma unroll
        for (int nt = 0; nt < 4; ++nt) acc[mt][nt] = (f32x4)0.0f;

    const char* Ap = (const char*)As;
#pragma unroll
    for (int ks = 0; ks < 4; ++ks) {
        int kb2 = ks * 64 + kg * 16;
        short8 af[4], bfr[4];
#pragma unroll
        for (int t = 0; t < 4; ++t) {
            int m = mbase + t * 16 + lr;
            af[t] = *(const short8*)(Ap + m * 256 + (kb2 ^ ((m & 15) << 4)));
            int n = nbase + t * 16 + lr;
            bfr[t] = *(const short8*)&Wt[n * D + ks * 32 + kg * 8];
        }
#pragma unroll
        for (int mt = 0; mt < 4; ++mt)
#pragma unroll
            for (int nt = 0; nt < 4; ++nt)
                acc[mt][nt] = __builtin_amdgcn_mfma_f32_16x16x32_bf16(af[mt], bfr[nt], acc[mt][nt], 0, 0, 0);
    }

    float bv[4];
#pragma unroll
    for (int nt = 0; nt < 4; ++nt) bv[nt] = bias[nbase + nt * 16 + lr];
#pragma unroll
    for (int mt = 0; mt < 4; ++mt) {
#pragma unroll
        for (int r = 0; r < 4; ++r) {
            int gm = row0 + mbase + mt * 16 + kg * 4 + r;
            if (gm < N_NODES) {
#pragma unroll
                for (int nt = 0; nt < 4; ++nt) {
                    int gn = nbase + nt * 16 + lr;
                    float z = acc[mt][nt][r] + bv[nt];
                    z = (z >= 0.f) ? z : 0.2f * z;
                    float o = z + bf2f((u32)xres[(size_t)gm * D + gn]);
                    xbout[(size_t)gm * D + gn] = f2bf(o);
                }
            }
        }
    }
}

// ---------------- pooling + final BN + fc ----------------

// batch is SORTED: detect boundaries with adjacent compares; no atomics.
__global__ void bounds_kernel(const int* __restrict__ batch, int* __restrict__ gs, int* __restrict__ ge) {
    int i = blockIdx.x * blockDim.x + threadIdx.x;
    if (i >= N_NODES) return;
    int b = batch[i];
    if (i == 0) {
        gs[b] = 0;
    } else {
        int bp = batch[i - 1];
        if (bp != b) { gs[b] = i; ge[bp] = i; }
    }
    if (i == N_NODES - 1) ge[b] = N_NODES;
}

__global__ void pool_kernel(const u16* __restrict__ xb, const int* __restrict__ gs,
                            const int* __restrict__ ge, float* __restrict__ pooled) {
    int g = blockIdx.x, f = threadIdx.x;
    int s = gs[g], e = ge[g];
    float a0 = 0.f, a1 = 0.f, a2 = 0.f, a3 = 0.f;
    int i = s;
    for (; i + 4 <= e; i += 4) {
        a0 += bf2f((u32)xb[(size_t)i * D + f]);
        a1 += bf2f((u32)xb[(size_t)(i + 1) * D + f]);
        a2 += bf2f((u32)xb[(size_t)(i + 2) * D + f]);
        a3 += bf2f((u32)xb[(size_t)(i + 3) * D + f]);
    }
    for (; i < e; ++i) a0 += bf2f((u32)xb[(size_t)i * D + f]);
    pooled[g * D + f] = (a0 + a1) + (a2 + a3);
}

// 128 blocks (one per feature) x 256 threads; shfl + LDS reduce.
__global__ void pooled_bn(const float* __restrict__ pooled, const float* __restrict__ g,
                          const float* __restrict__ b, float* __restrict__ pscale,
                          float* __restrict__ pshift) {
    int c = blockIdx.x;
    int t = threadIdx.x;
    float s = 0.f, q = 0.f;
    for (int gi = t; gi < N_GRAPHS; gi += 256) {
        float v = pooled[gi * D + c];
        s += v; q += v * v;
    }
#pragma unroll
    for (int off = 32; off > 0; off >>= 1) {
        s += __shfl_down(s, off);
        q += __shfl_down(q, off);
    }
    __shared__ float ss[4], qq[4];
    int lane = t & 63, w = t >> 6;
    if (lane == 0) { ss[w] = s; qq[w] = q; }
    __syncthreads();
    if (t == 0) {
        float S = (ss[0] + ss[1]) + (ss[2] + ss[3]);
        float Q = (qq[0] + qq[1]) + (qq[2] + qq[3]);
        float m = S / N_GRAPHS;
        float var = fmaxf(Q / N_GRAPHS - m * m, 0.f);
        float sc = g[c] * rsqrtf(var + EPS);
        pscale[c] = sc;
        pshift[c] = b[c] - m * sc;
    }
}

__global__ void out_kernel(const float* __restrict__ pooled, const float* __restrict__ pscale,
                           const float* __restrict__ pshift, const float* __restrict__ fcW,
                           const float* __restrict__ fcb, float* __restrict__ out) {
    int idx = blockIdx.x * blockDim.x + threadIdx.x;
    if (idx >= N_GRAPHS * LATENT) return;
    int g = idx >> 6, j = idx & 63;
    float acc = fcb[j];
    for (int c = 0; c < D; ++c) {
        float pv = pooled[g * D + c] * pscale[c] + pshift[c];
        acc += pv * fcW[c * LATENT + j];
    }
    out[idx] = acc;
}

// ---------------- launch ----------------

extern "C" void kernel_launch(void* const* d_in, const int* in_sizes, int n_in,
                              void* d_out, int out_size, void* d_ws, size_t ws_size,
                              hipStream_t stream) {
    const float* x_in = (const float*)d_in[0];
    const int* edges  = (const int*)d_in[1];
    const int* batch  = (const int*)d_in[2];
    const float* W1   = (const float*)d_in[3];
    const float* b1   = (const float*)d_in[4];
    const float* g1   = (const float*)d_in[5];
    const float* bt1  = (const float*)d_in[6];
    const float* W2   = (const float*)d_in[7];
    const float* b2   = (const float*)d_in[8];
    const float* bng  = (const float*)d_in[9];
    const float* bnb  = (const float*)d_in[10];
    const float* fcW  = (const float*)d_in[11];
    const float* fcb  = (const float*)d_in[12];
    float* out = (float*)d_out;
    const int* srcp = edges;
    const int* dstp = edges + N_EDGES;

    char* p = (char*)d_ws;
    auto alloc = [&](size_t bytes) -> char* {
        char* r = p;
        p += (bytes + 511) & ~(size_t)511;
        return r;
    };
    u16*   XB      = (u16*)alloc((size_t)N_NODES * D * 2);     // bf16 x stream (residual+gather)
    u16*   HB      = (u16*)alloc((size_t)N_NODES * D * 2);     // H between agg_gemm1 and gemm2
    int*   csr     = (int*)alloc((size_t)N_EDGES * 4);
    u32*   ebp     = (u32*)alloc((size_t)N_EDGES * 4);         // packed (src<<9)|dst_low
    int*   deg     = (int*)alloc((size_t)N_NODES * 4);
    int*   offsets = (int*)alloc((size_t)(N_NODES + 1) * 4);
    int*   bsum    = (int*)alloc((size_t)NB * 4);
    int*   boff    = (int*)alloc((size_t)NB * 4);
    int*   bhist   = (int*)alloc((size_t)NBUCK * 4);
    int*   bstart  = (int*)alloc((size_t)(NBUCK + 1) * 4);
    int*   gbcur   = (int*)alloc((size_t)NBUCK * 4);
    u16*   Wtb     = (u16*)alloc((size_t)6 * D * D * 2);       // bf16 transposed weights
    float* colsumA = (float*)alloc((size_t)6 * 256 * 4);       // [l]: sum@l*256, sq@l*256+128
    int*   gs      = (int*)alloc(N_GRAPHS * 4);
    int*   ge      = (int*)alloc(N_GRAPHS * 4);
    float* pooled  = (float*)alloc((size_t)N_GRAPHS * D * 4);
    float* pscale  = (float*)alloc(D * 4);
    float* pshift  = (float*)alloc(D * 4);

    init_misc<<<7 + CONVX_BLOCKS, 256, 0, stream>>>(W1, W2, Wtb, x_in, XB, colsumA,
                                                    bhist, gs, ge);

    const int EGRID = (N_EDGES + 4095) / 4096;   // 391
    bucket_hist<<<EGRID, 256, 0, stream>>>(dstp, bhist);
    bucket_scan<<<1, 256, 0, stream>>>(bhist, bstart, gbcur);
    bucket_scatter<<<EGRID, 256, 0, stream>>>(srcp, dstp, gbcur, ebp);
    hist_local<<<NBUCK, 256, 0, stream>>>(ebp, bstart, deg);
    scan_block_sum<<<NB, 256, 0, stream>>>(deg, bsum);
    scan_top<<<1, 512, 0, stream>>>(bsum, boff);
    scan_apply<<<NB, 256, 0, stream>>>(deg, boff, offsets);
    csr_fill_local<<<NBUCK, 256, 0, stream>>>(ebp, bstart, offsets, csr);

    const int GEMM_GRID = (N_NODES + 127) / 128;      // 782
    for (int l = 0; l < 3; ++l) {
        agg_gemm1_mfma<<<GEMM_GRID, 256, 0, stream>>>(XB, csr, offsets,
                                                      Wtb + (size_t)l * D * D, b1 + l * D, HB,
                                                      colsumA + l * 256, colsumA + l * 256 + 128);
        gemm2_mfma<<<GEMM_GRID, 256, 0, stream>>>(HB, Wtb + (size_t)(3 + l) * D * D, b2 + l * D,
                                                  colsumA + l * 256, colsumA + l * 256 + 128,
                                                  g1 + l * D, bt1 + l * D, XB, XB);
    }

    bounds_kernel<<<NB, 256, 0, stream>>>(batch, gs, ge);
    pool_kernel<<<N_GRAPHS, D, 0, stream>>>(XB, gs, ge, pooled);
    pooled_bn<<<D, 256, 0, stream>>>(pooled, bng, bnb, pscale, pshift);
    out_kernel<<<(N_GRAPHS * LATENT + 255) / 256, 256, 0, stream>>>(pooled, pscale, pshift,
                                                                    fcW, fcb, out);
}